// Round 3
// baseline (272.744 us; speedup 1.0000x reference)
//
#include <hip/hip_runtime.h>

// Problem constants
#define BB   2
#define SS   4096
#define DD   1024
#define HH   16
#define DHH  64
#define WW   256
#define GG   64
#define NBLK 16    // S/W

typedef unsigned short ushort_t;
typedef short  s16x8 __attribute__((ext_vector_type(8)));
typedef float  f32x4 __attribute__((ext_vector_type(4)));

// 0.125 * log2(e): folded into q at QKV-GEMM epilogue time so attention's
// softmax is a bare exp2 of the MFMA output.
#define QSCALE 0.18033688011112042f

// fp32 -> bf16 round-to-nearest-even, raw bits
__device__ __forceinline__ ushort_t f2b(float f) {
  unsigned int u = __builtin_bit_cast(unsigned int, f);
  unsigned int r = (u + 0x7fffu + ((u >> 16) & 1u)) >> 16;
  return (ushort_t)r;
}

// single-op fp32 -> bf16 (RNE) via v_cvt_pk_bf16_f32, low half used
__device__ __forceinline__ ushort_t f2b1(float f) {
  unsigned int r;
  asm("v_cvt_pk_bf16_f32 %0, %1, %2" : "=v"(r) : "v"(f), "v"(f));
  return (ushort_t)r;
}

// 2^x via v_exp_f32 (NOT __exp2f — that name collides with glibc math.h).
__device__ __forceinline__ float exp2f_fast(float x) {
  return __builtin_amdgcn_exp2f(x);
}

// Async 16B global->LDS DMA. LDS dst must be wave-uniform base + lane*16.
__device__ __forceinline__ void gld16(const void* g, void* l) {
  __builtin_amdgcn_global_load_lds(
      (const __attribute__((address_space(1))) void*)g,
      (__attribute__((address_space(3))) void*)l, 16, 0, 0);
}

// ---------------------------------------------------------------------------
// x (fp32) -> bf16, flat. 4096 blocks x 256 thr x 8 elems.
// ---------------------------------------------------------------------------
__global__ __launch_bounds__(256) void xcast(
    const float* __restrict__ x, ushort_t* __restrict__ xb) {
  size_t i = ((size_t)blockIdx.x * 256 + threadIdx.x) * 8;
  float4 f0 = *(const float4*)&x[i];
  float4 f1 = *(const float4*)&x[i + 4];
  ushort_t t[8];
  t[0] = f2b(f0.x); t[1] = f2b(f0.y); t[2] = f2b(f0.z); t[3] = f2b(f0.w);
  t[4] = f2b(f1.x); t[5] = f2b(f1.y); t[6] = f2b(f1.z); t[7] = f2b(f1.w);
  *(uint4*)&xb[i] = *(const uint4*)t;
}

// ---------------------------------------------------------------------------
// Transpose + fp32->bf16 the four weight matrices into (n,k) bf16 layout.
// ---------------------------------------------------------------------------
__global__ __launch_bounds__(256) void transpose_w(
    const float* __restrict__ Wq, const float* __restrict__ Wk,
    const float* __restrict__ Wv, const float* __restrict__ Wo,
    ushort_t* __restrict__ outBase) {
  const float* src = (blockIdx.z == 0) ? Wq : (blockIdx.z == 1) ? Wk
                    : (blockIdx.z == 2) ? Wv : Wo;
  ushort_t* dst = outBase + (size_t)blockIdx.z * (1024 * 1024);
  __shared__ __align__(16) ushort_t t[64][72];
  const int tid = threadIdx.x;
  const int bx = blockIdx.x * 64, by = blockIdx.y * 64;
  const int c4 = (tid & 15) * 4;
  const int r16 = tid >> 4;
  for (int rr = r16; rr < 64; rr += 16) {
    float4 f = *(const float4*)&src[(size_t)(by + rr) * 1024 + bx + c4];
    t[c4 + 0][rr] = f2b(f.x);
    t[c4 + 1][rr] = f2b(f.y);
    t[c4 + 2][rr] = f2b(f.z);
    t[c4 + 3][rr] = f2b(f.w);
  }
  __syncthreads();
  const int sr = tid >> 3;
  const int sc = (tid & 7) * 8;
  for (int rr = sr; rr < 64; rr += 32) {
    *(uint4*)&dst[(size_t)(bx + rr) * 1024 + by + sc] = *(const uint4*)&t[rr][sc];
  }
}

// ---------------------------------------------------------------------------
// GEMM, 256x256 tile, 8-phase pipelined schedule (m201-style template).
// RETRY of round-2 submission: bench infra failed ("container failed twice",
// no compile/correctness signal); schedule ledger re-audited — barriers
// uniform, vmcnt ledger sound, addresses in-bounds. Resubmitted unchanged.
//   C(M,N) = A(M,K) @ Bt(N,K)^T, bf16 in, fp32 acc. K multiple of 64, >= 128.
//   512 threads = 8 waves (2M x 4N), per-wave output 128x64, acc[8][4].
//   LDS: 2 buffers x {A,B} x {kk-half 0,1} slabs of 256 rows x 32 cols bf16
//        (16 KiB each) = 128 KiB. Each slab staged by ONE phase's
//        2 x global_load_lds per thread (linear dest, inverse-swizzled
//        global source; read side applies chunk ^= (row>>1)&3).
//   Phases per K-tile: p1=(kk0, m 0..3)+B(kk0)-read, p2=(kk0, m 4..7),
//        p3=(kk1, m 0..3)+B(kk1)-read, p4=(kk1, m 4..7).
//   Stage slots (into buf[kt&1] unless noted): p1: A-kk1(kt+1)->buf^1,
//        p2: B-kk0(kt+2), p3: A-kk0(kt+2), p4: B-kk1(kt+2).
//   Slab death: B-kk0 after p1 (B-frags reused in regs for p2), A-kk0 after
//        p2, B-kk1 after p3, A-kk1 after p4 -> every stage targets a dead
//        slab (>=1 phase gap; end-of-phase barrier orders it).
//   vmcnt(6) once per K-tile at p4 (3 half-tiles in flight, never 0 in the
//        main loop); guarantees stages <= (kt,p1) have landed, which is all
//        four slabs of tile kt+1. Epilogue: vmcnt(0) at (NT-2,p4).
// MODE 0: N=3072 QKV; q,k head-split (B,H,S,DH); v TRANSPOSED (B,H,DH,S).
//         q additionally pre-scaled by QSCALE.
// MODE 1: fp32 row-major C to Of.
// ---------------------------------------------------------------------------
template <int MODE>
__global__ __launch_bounds__(512, 2) void gemm256(
    const ushort_t* __restrict__ A, const ushort_t* __restrict__ Bt,
    ushort_t* __restrict__ O0, ushort_t* __restrict__ O1,
    ushort_t* __restrict__ O2, float* __restrict__ Of, int K) {
  // [buf][kkh][256*32] slabs, each 16 KiB, row-major 64B rows.
  __shared__ __align__(16) ushort_t As[2][2][256 * 32];
  __shared__ __align__(16) ushort_t Bs[2][2][256 * 32];

  const int tid  = threadIdx.x;        // 0..511
  const int lane = tid & 63;
  const int w    = tid >> 6;           // 0..7
  const int quad = lane >> 4;          // 0..3
  const int l16  = lane & 15;
  const int wr   = w >> 2;             // 0..1  (M)
  const int wc   = w & 3;              // 0..3  (N)
  const int bm   = blockIdx.x * 256;
  const int bn   = blockIdx.y * 256;

  // Staging precompute: thread stages LDS (row = i*128 + tid>>2, chunk = tid&3);
  // the global source chunk is inverse-swizzled so reads can XOR-deswizzle.
  const int srow = tid >> 2;                        // 0..127
  const int sch  = (tid & 3) ^ ((srow >> 1) & 3);   // source 16B chunk in row
  const ushort_t* Ag = A + (size_t)(bm + srow) * K + sch * 8;
  const ushort_t* Bg = Bt + (size_t)(bn + srow) * K + sch * 8;

  // Fragment-read swizzle: chunk = quad ^ ((row>>1)&3); row = 16*t + l16 =>
  // (row>>1)&3 = (l16>>1)&3 (per-lane constant).
  const int chofs = ((quad ^ ((l16 >> 1) & 3)) << 3);   // element offset of chunk

  auto stage = [&](ushort_t* slab, const ushort_t* g) {
    gld16(g, &slab[tid * 8]);                      // rows 0..127 of slab
    gld16(g + (size_t)128 * K, &slab[4096 + tid * 8]);  // rows 128..255
  };

  f32x4 acc[8][4] = {};
  s16x8 afrag[4], bfrag[4];

  auto ldA = [&](int buf, int kkh, int i) {
    const int row = wr * 128 + i * 16 + l16;
    return *(const s16x8*)&As[buf][kkh][row * 32 + chofs];
  };
  auto ldB = [&](int buf, int kkh, int j) {
    const int row = wc * 64 + j * 16 + l16;
    return *(const s16x8*)&Bs[buf][kkh][row * 32 + chofs];
  };
  auto mfma16 = [&](int ih) {
    __builtin_amdgcn_s_setprio(1);
#pragma unroll
    for (int t = 0; t < 4; t++)
#pragma unroll
      for (int j = 0; j < 4; j++)
        acc[ih * 4 + t][j] = __builtin_amdgcn_mfma_f32_16x16x32_bf16(
            afrag[t], bfrag[j], acc[ih * 4 + t][j], 0, 0, 0);
    __builtin_amdgcn_s_setprio(0);
  };

  const int NT = K >> 6;   // K-tiles (=16 here); requires NT >= 2

  // ---- prologue: tile0 (4 slabs) + tile1 (3 slabs); A-kk1(1) comes at (0,p1)
  stage(&Bs[0][0][0], Bg);
  stage(&As[0][0][0], Ag);
  stage(&Bs[0][1][0], Bg + 32);
  stage(&As[0][1][0], Ag + 32);
  asm volatile("s_waitcnt vmcnt(4)" ::: "memory");
  stage(&Bs[1][0][0], Bg + 64);
  stage(&As[1][0][0], Ag + 64);
  stage(&Bs[1][1][0], Bg + 96);
  asm volatile("s_waitcnt vmcnt(6)" ::: "memory");
  __builtin_amdgcn_s_barrier();

#pragma unroll 1
  for (int kt = 0; kt < NT; ++kt) {
    const int buf = kt & 1;
    // ---------- phase 1: kk0, m 0..3 (reads B kk0) ----------
#pragma unroll
    for (int j = 0; j < 4; j++) bfrag[j] = ldB(buf, 0, j);
#pragma unroll
    for (int t = 0; t < 4; t++) afrag[t] = ldA(buf, 0, t);
    if (kt + 1 < NT) stage(&As[buf ^ 1][1][0], Ag + (size_t)(kt + 1) * 64 + 32);
    __builtin_amdgcn_s_barrier();
    asm volatile("s_waitcnt lgkmcnt(0)" ::: "memory");
    mfma16(0);
    __builtin_amdgcn_s_barrier();
    // ---------- phase 2: kk0, m 4..7 (B reused in regs) ----------
#pragma unroll
    for (int t = 0; t < 4; t++) afrag[t] = ldA(buf, 0, 4 + t);
    if (kt + 2 < NT) stage(&Bs[buf][0][0], Bg + (size_t)(kt + 2) * 64);
    __builtin_amdgcn_s_barrier();
    asm volatile("s_waitcnt lgkmcnt(0)" ::: "memory");
    mfma16(1);
    __builtin_amdgcn_s_barrier();
    // ---------- phase 3: kk1, m 0..3 (reads B kk1) ----------
#pragma unroll
    for (int j = 0; j < 4; j++) bfrag[j] = ldB(buf, 1, j);
#pragma unroll
    for (int t = 0; t < 4; t++) afrag[t] = ldA(buf, 1, t);
    if (kt + 2 < NT) stage(&As[buf][0][0], Ag + (size_t)(kt + 2) * 64);
    __builtin_amdgcn_s_barrier();
    asm volatile("s_waitcnt lgkmcnt(0)" ::: "memory");
    mfma16(0);
    __builtin_amdgcn_s_barrier();
    // ---------- phase 4: kk1, m 4..7; counted vmcnt ----------
#pragma unroll
    for (int t = 0; t < 4; t++) afrag[t] = ldA(buf, 1, 4 + t);
    if (kt + 2 < NT) {
      stage(&Bs[buf][1][0], Bg + (size_t)(kt + 2) * 64 + 32);
      asm volatile("s_waitcnt vmcnt(6)" ::: "memory");
    } else if (kt + 1 < NT) {
      asm volatile("s_waitcnt vmcnt(0)" ::: "memory");   // drain last stage
    }
    __builtin_amdgcn_s_barrier();
    asm volatile("s_waitcnt lgkmcnt(0)" ::: "memory");
    mfma16(1);
    __builtin_amdgcn_s_barrier();
  }

  // Epilogue. C/D layout: row = quad*4 + reg, col = lane&15.
#pragma unroll
  for (int i = 0; i < 8; i++) {
#pragma unroll
    for (int j = 0; j < 4; j++) {
#pragma unroll
      for (int r = 0; r < 4; r++) {
        int m = bm + wr * 128 + i * 16 + quad * 4 + r;
        int n = bn + wc * 64 + j * 16 + l16;
        float av = acc[i][j][r];
        if (MODE == 0) {
          int n1 = n & 1023;
          int h = n1 >> 6, dh = n1 & 63;
          int b = m >> 12, s = m & 4095;
          if (n < 1024) {
            O0[(((size_t)b * HH + h) * SS + s) * DHH + dh] = f2b(av * QSCALE);  // q (pre-scaled)
          } else if (n < 2048) {
            O1[(((size_t)b * HH + h) * SS + s) * DHH + dh] = f2b(av);           // k: (B,H,S,DH)
          } else {
            O2[(((size_t)b * HH + h) * DHH + dh) * SS + s] = f2b(av);           // v: (B,H,DH,S)
          }
        } else {
          Of[(size_t)m * DD + n] = av;   // fp32 output
        }
      }
    }
  }
}

// ---------------------------------------------------------------------------
// Attention v3: barrier-free, wave-independent, software-pipelined.
// (unchanged — verified at 268.6 µs total in round 1)
// ---------------------------------------------------------------------------
__global__ __launch_bounds__(256, 2) void attn_kernel(
    const ushort_t* __restrict__ q, const ushort_t* __restrict__ k,
    const ushort_t* __restrict__ vT, ushort_t* __restrict__ out) {
  const int blk = blockIdx.x;
  const int h   = blockIdx.y;
  const int b   = blockIdx.z;
  const int tid  = threadIdx.x;
  const int lane = tid & 63;
  const int w    = tid >> 6;
  const int quad = lane >> 4;
  const int l16  = lane & 15;

  const size_t bh = ((size_t)b * HH + h) * SS * DHH;
  const ushort_t* qb  = q + bh;
  const ushort_t* kb  = k + bh;
  const ushort_t* vtb = vT + bh;   // layout [dh][s], row stride SS

  __shared__ __align__(16) ushort_t Ps[4][64 * 64];   // per-wave P tiles
  ushort_t* Pw = &Ps[w][0];

  const int q0 = blk * WW + w * 64;

  // P-tile element offsets, layout: elem(row,col) = (col>>3)*512 + row*8 + (col&7)
  const int wbase = ((l16 >> 3) << 9) + (quad << 5) + (l16 & 7);  // write: +nt*1024+mt*128+r*8
  const int rbase = (quad << 9) + (l16 << 3);                     // read:  +(ll>>3)*512+mt*128

  // Q fragments (A-operand: m = lane&15, k = x*32 + quad*8 + j)
  s16x8 aq[4][2];
#pragma unroll
  for (int mt = 0; mt < 4; mt++)
#pragma unroll
    for (int x = 0; x < 2; x++)
      aq[mt][x] = *(const s16x8*)&qb[(size_t)(q0 + mt * 16 + l16) * DHH + x * 32 + quad * 8];

  f32x4 oacc[4][4] = {};
  f32x4 rsacc[4] = {};

  s16x8 vone;
#pragma unroll
  for (int j = 0; j < 8; j++) vone[j] = (short)0x3F80;   // bf16 1.0

  s16x8 bk[4][2];   // K fragments (current / prefetched next chunk)
  s16x8 bv[4][2];   // V^T fragments (current chunk)

  auto LOADK = [&](int j0s) {
    const ushort_t* kc = kb + (size_t)j0s * DHH;
#pragma unroll
    for (int nt = 0; nt < 4; nt++)
#pragma unroll
      for (int x = 0; x < 2; x++)
        bk[nt][x] = *(const s16x8*)&kc[(nt * 16 + l16) * DHH + x * 32 + quad * 8];
  };
  auto LOADV = [&](int j0s) {
    const ushort_t* vc = vtb + j0s;
#pragma unroll
    for (int dt = 0; dt < 4; dt++)
#pragma unroll
      for (int x = 0; x < 2; x++)
        bv[dt][x] = *(const s16x8*)&vc[(size_t)(dt * 16 + l16) * SS + x * 32 + quad * 8];
  };

  const int jlo = (q0 - (int)WW < (int)GG) ? (int)GG : (q0 - (int)WW);
  int jhi = q0 + (int)WW;
  if (jhi > SS - 64) jhi = SS - 64;

  int j0  = jlo;
  int j0u = __builtin_amdgcn_readfirstlane(j0);
  LOADK(j0u);

  bool last = false;
  while (!last) {
    int jn = j0 + 64;
    if (j0 == 0) { last = true; jn = 0; }
    else if (jn > jhi) jn = 0;               // wrap to the global chunk

    LOADV(j0u);                               // issued early; needed in PV

    const int dlt = j0 - q0;
    const bool needmask = (j0 != 0) && (dlt < -193 || dlt > 193);

    // --- QK^T + exp2 + P-write (per-wave LDS, immediate-offset addressing)
#pragma unroll
    for (int nt = 0; nt < 4; nt++) {
      const int j = j0 + nt * 16 + l16;
#pragma unroll
      for (int mt = 0; mt < 4; mt++) {
        f32x4 s4 = {0.f, 0.f, 0.f, 0.f};
        s4 = __builtin_amdgcn_mfma_f32_16x16x32_bf16(aq[mt][0], bk[nt][0], s4, 0, 0, 0);
        s4 = __builtin_amdgcn_mfma_f32_16x16x32_bf16(aq[mt][1], bk[nt][1], s4, 0, 0, 0);
#pragma unroll
        for (int r = 0; r < 4; r++) {
          float p;
          if (needmask) {
            int i = q0 + mt * 16 + quad * 4 + r;
            int d = j - i;
            p = (d <= (int)WW && d >= -(int)WW) ? exp2f_fast(s4[r]) : 0.0f;
          } else {
            p = exp2f_fast(s4[r]);
          }
          Pw[wbase + nt * 1024 + mt * 128 + r * 8] = f2b1(p);
        }
      }
    }

    // --- prefetch next chunk's K while exp/P/PV run
    int jnu = __builtin_amdgcn_readfirstlane(jn);
    if (!last) LOADK(jnu);

    // --- PV + ones-MFMA row sums
    __builtin_amdgcn_s_setprio(1);
#pragma unroll
    for (int ll = 0; ll < 64; ll += 32) {
      s16x8 ap[4];
#pragma unroll
      for (int mt = 0; mt < 4; mt++)
        ap[mt] = *(const s16x8*)&Pw[rbase + (ll >> 3) * 512 + mt * 128];
#pragma unroll
      for (int mt = 0; mt < 4; mt++) {
        rsacc[mt] = __builtin_amdgcn_mfma_f32_16x16x32_bf16(ap[mt], vone, rsacc[mt], 0, 0, 0);
#pragma unroll
        for (int dt = 0; dt < 4; dt++)
          oacc[mt][dt] = __builtin_amdgcn_mfma_f32_16x16x32_bf16(ap[mt], bv[dt][ll >> 5], oacc[mt][dt], 0, 0, 0);
      }
    }
    __builtin_amdgcn_s_setprio(0);

    j0 = jn; j0u = jnu;
  }

  // Normalize + store (rsacc C-layout matches oacc rows: quad*4+r).
#pragma unroll
  for (int mt = 0; mt < 4; mt++) {
#pragma unroll
    for (int r = 0; r < 4; r++) {
      float inv = __builtin_amdgcn_rcpf(rsacc[mt][r]);
      int srow2 = q0 + mt * 16 + quad * 4 + r;
      size_t orow = ((size_t)b * SS + srow2) * DD + h * DHH;
#pragma unroll
      for (int dt = 0; dt < 4; dt++)
        out[orow + dt * 16 + l16] = f2b1(oacc[mt][dt][r] * inv);
    }
  }
}

// ---------------------------------------------------------------------------
extern "C" void kernel_launch(void* const* d_in, const int* in_sizes, int n_in,
                              void* d_out, int out_size, void* d_ws, size_t ws_size,
                              hipStream_t stream) {
  const float *x, *Wq, *Wk, *Wv, *Wo;
  if (n_in == 5 && in_sizes[4] == 8388608) {   // alphabetical fallback
    Wk = (const float*)d_in[0]; Wo = (const float*)d_in[1];
    Wq = (const float*)d_in[2]; Wv = (const float*)d_in[3];
    x  = (const float*)d_in[4];
  } else {                                      // dict order (confirmed round 5/6)
    x  = (const float*)d_in[0]; Wq = (const float*)d_in[1];
    Wk = (const float*)d_in[2]; Wv = (const float*)d_in[3];
    Wo = (const float*)d_in[4];
  }
  float* out = (float*)d_out;   // fp32 output (confirmed round 6)

  // Workspace (72 MiB, proven available):
  // [WqT|WkT|WvT] 6MiB | WoT 2MiB | q 16MiB | k 16MiB | vT 16MiB | attn/xb 16MiB
  // xb (bf16 x) shares the attn slot: consumed by gemm<0> before attn writes.
  char* ws = (char*)d_ws;
  ushort_t* wqkvT = (ushort_t*)(ws);
  ushort_t* woT   = (ushort_t*)(ws + 6291456);
  ushort_t* qbuf  = (ushort_t*)(ws + 8388608);
  ushort_t* kbuf  = (ushort_t*)(ws + 8388608 + 16777216);
  ushort_t* vbuf  = (ushort_t*)(ws + 8388608 + 2 * 16777216);
  ushort_t* attn  = (ushort_t*)(ws + 8388608 + 3 * 16777216);
  ushort_t* xb    = attn;   // alias, lifetime-disjoint

  xcast<<<dim3(4096), 256, 0, stream>>>(x, xb);
  transpose_w<<<dim3(16, 16, 4), 256, 0, stream>>>(Wq, Wk, Wv, Wo, wqkvT);
  gemm256<0><<<dim3(32, 12), 512, 0, stream>>>(xb, wqkvT, qbuf, kbuf, vbuf, nullptr, 1024);
  attn_kernel<<<dim3(NBLK, HH, BB), 256, 0, stream>>>(qbuf, kbuf, vbuf, attn);
  gemm256<1><<<dim3(32, 4), 512, 0, stream>>>(attn, woT, nullptr, nullptr, nullptr, out, 1024);
}

// Round 4
// 245.905 us; speedup vs baseline: 1.1091x; 1.1091x over previous
//
#include <hip/hip_runtime.h>

// Problem constants
#define BB   2
#define SS   4096
#define DD   1024
#define HH   16
#define DHH  64
#define WW   256
#define GG   64
#define NBLK 16    // S/W

typedef unsigned short ushort_t;
typedef short  s16x8 __attribute__((ext_vector_type(8)));
typedef float  f32x4 __attribute__((ext_vector_type(4)));

// 0.125 * log2(e): folded into q at QKV-GEMM epilogue time so attention's
// softmax is a bare exp2 of the MFMA output.
#define QSCALE 0.18033688011112042f

// fp32 -> bf16 round-to-nearest-even, raw bits
__device__ __forceinline__ ushort_t f2b(float f) {
  unsigned int u = __builtin_bit_cast(unsigned int, f);
  unsigned int r = (u + 0x7fffu + ((u >> 16) & 1u)) >> 16;
  return (ushort_t)r;
}

// single-op fp32 -> bf16 (RNE) via v_cvt_pk_bf16_f32, low half used
__device__ __forceinline__ ushort_t f2b1(float f) {
  unsigned int r;
  asm("v_cvt_pk_bf16_f32 %0, %1, %2" : "=v"(r) : "v"(f), "v"(f));
  return (ushort_t)r;
}

// 2^x via v_exp_f32 (NOT __exp2f — that name collides with glibc math.h).
__device__ __forceinline__ float exp2f_fast(float x) {
  return __builtin_amdgcn_exp2f(x);
}

// Async 16B global->LDS DMA. LDS dst must be wave-uniform base + lane*16.
__device__ __forceinline__ void gld16(const void* g, void* l) {
  __builtin_amdgcn_global_load_lds(
      (const __attribute__((address_space(1))) void*)g,
      (__attribute__((address_space(3))) void*)l, 16, 0, 0);
}

// ---------------------------------------------------------------------------
// x (fp32) -> bf16, flat. 4096 blocks x 256 thr x 8 elems.
// ---------------------------------------------------------------------------
__global__ __launch_bounds__(256) void xcast(
    const float* __restrict__ x, ushort_t* __restrict__ xb) {
  size_t i = ((size_t)blockIdx.x * 256 + threadIdx.x) * 8;
  float4 f0 = *(const float4*)&x[i];
  float4 f1 = *(const float4*)&x[i + 4];
  ushort_t t[8];
  t[0] = f2b(f0.x); t[1] = f2b(f0.y); t[2] = f2b(f0.z); t[3] = f2b(f0.w);
  t[4] = f2b(f1.x); t[5] = f2b(f1.y); t[6] = f2b(f1.z); t[7] = f2b(f1.w);
  *(uint4*)&xb[i] = *(const uint4*)t;
}

// ---------------------------------------------------------------------------
// Transpose + fp32->bf16 the four weight matrices into (n,k) bf16 layout.
// ---------------------------------------------------------------------------
__global__ __launch_bounds__(256) void transpose_w(
    const float* __restrict__ Wq, const float* __restrict__ Wk,
    const float* __restrict__ Wv, const float* __restrict__ Wo,
    ushort_t* __restrict__ outBase) {
  const float* src = (blockIdx.z == 0) ? Wq : (blockIdx.z == 1) ? Wk
                    : (blockIdx.z == 2) ? Wv : Wo;
  ushort_t* dst = outBase + (size_t)blockIdx.z * (1024 * 1024);
  __shared__ __align__(16) ushort_t t[64][72];
  const int tid = threadIdx.x;
  const int bx = blockIdx.x * 64, by = blockIdx.y * 64;
  const int c4 = (tid & 15) * 4;
  const int r16 = tid >> 4;
  for (int rr = r16; rr < 64; rr += 16) {
    float4 f = *(const float4*)&src[(size_t)(by + rr) * 1024 + bx + c4];
    t[c4 + 0][rr] = f2b(f.x);
    t[c4 + 1][rr] = f2b(f.y);
    t[c4 + 2][rr] = f2b(f.z);
    t[c4 + 3][rr] = f2b(f.w);
  }
  __syncthreads();
  const int sr = tid >> 3;
  const int sc = (tid & 7) * 8;
  for (int rr = sr; rr < 64; rr += 32) {
    *(uint4*)&dst[(size_t)(bx + rr) * 1024 + by + sc] = *(const uint4*)&t[rr][sc];
  }
}

// ---------------------------------------------------------------------------
// GEMM, 256x256 tile, 8-phase pipelined schedule. This round's changes:
//  (1) 2-D super-tile XCD swizzle: id=bx+32*by; xcd=id&7; seq=id>>3;
//      nx=4*xcd+(seq&3), ny=seq>>2. XCD k owns x in [4k,4k+4) across all y,
//      y-major -> concurrent per-XCD K-slice footprint ~4 A-slabs + 8
//      B-slabs (~384 KB << 4 MiB L2); each L3 line pulled once per XCD.
//      Requires gridDim.x == 32 and total blocks % 8 == 0 (both grids ok).
//      Bijective: nx encodes (xcd, seq&3), ny encodes seq>>2.
//  (2) MODE0 v-blocks (bn >= 2048): epilogue via LDS transpose (two
//      128-col passes in the now-dead 128 KiB LDS) -> coalesced 16B stores
//      instead of 2B stores at 8 KB stride (16-line divergence per wave).
// Schedule (unchanged, verified round 3): 4 phases/K-tile, stage slots
// p1:A-kk1(kt+1)^1, p2:B-kk0(kt+2), p3:A-kk0(kt+2), p4:B-kk1(kt+2)+vmcnt(6);
// barriers uniform; epilogue drain vmcnt(0) at (NT-2,p4).
// MODE 0: N=3072 QKV; q,k head-split (B,H,S,DH); v TRANSPOSED (B,H,DH,S).
//         q additionally pre-scaled by QSCALE.
// MODE 1: fp32 row-major C to Of.
// ---------------------------------------------------------------------------
template <int MODE>
__global__ __launch_bounds__(512, 2) void gemm256(
    const ushort_t* __restrict__ A, const ushort_t* __restrict__ Bt,
    ushort_t* __restrict__ O0, ushort_t* __restrict__ O1,
    ushort_t* __restrict__ O2, float* __restrict__ Of, int K) {
  // Flat 128 KiB LDS; carved into 8 slabs of 8192 ushorts (16 KiB) for the
  // main loop, re-used whole as a 256x136 transpose tile in the v-epilogue.
  __shared__ __align__(16) ushort_t SH[65536];

  const int tid  = threadIdx.x;        // 0..511
  const int lane = tid & 63;
  const int w    = tid >> 6;           // 0..7
  const int quad = lane >> 4;          // 0..3
  const int l16  = lane & 15;
  const int wr   = w >> 2;             // 0..1  (M)
  const int wc   = w & 3;              // 0..3  (N)

  // ---- 2-D super-tile XCD swizzle (gridDim.x must be 32) ----
  const int id  = blockIdx.x + (gridDim.x * blockIdx.y);
  const int xcd = id & 7;
  const int seq = id >> 3;
  const int nx  = (xcd << 2) + (seq & 3);
  const int ny  = seq >> 2;
  const int bm  = nx * 256;
  const int bn  = ny * 256;

  auto Aslab = [&](int buf, int kkh) -> ushort_t* {
    return &SH[(buf * 2 + kkh) * 8192];
  };
  auto Bslab = [&](int buf, int kkh) -> ushort_t* {
    return &SH[32768 + (buf * 2 + kkh) * 8192];
  };

  // Staging precompute: thread stages LDS (row = i*128 + tid>>2, chunk = tid&3);
  // the global source chunk is inverse-swizzled so reads can XOR-deswizzle.
  const int srow = tid >> 2;                        // 0..127
  const int sch  = (tid & 3) ^ ((srow >> 1) & 3);   // source 16B chunk in row
  const ushort_t* Ag = A + (size_t)(bm + srow) * K + sch * 8;
  const ushort_t* Bg = Bt + (size_t)(bn + srow) * K + sch * 8;

  // Fragment-read swizzle: chunk = quad ^ ((row>>1)&3); row = 16*t + l16 =>
  // (row>>1)&3 = (l16>>1)&3 (per-lane constant).
  const int chofs = ((quad ^ ((l16 >> 1) & 3)) << 3);   // element offset of chunk

  auto stage = [&](ushort_t* slab, const ushort_t* g) {
    gld16(g, &slab[tid * 8]);                           // rows 0..127 of slab
    gld16(g + (size_t)128 * K, &slab[4096 + tid * 8]);  // rows 128..255
  };

  f32x4 acc[8][4] = {};
  s16x8 afrag[4], bfrag[4];

  auto ldA = [&](int buf, int kkh, int i) {
    const int row = wr * 128 + i * 16 + l16;
    return *(const s16x8*)&Aslab(buf, kkh)[row * 32 + chofs];
  };
  auto ldB = [&](int buf, int kkh, int j) {
    const int row = wc * 64 + j * 16 + l16;
    return *(const s16x8*)&Bslab(buf, kkh)[row * 32 + chofs];
  };
  auto mfma16 = [&](int ih) {
    __builtin_amdgcn_s_setprio(1);
#pragma unroll
    for (int t = 0; t < 4; t++)
#pragma unroll
      for (int j = 0; j < 4; j++)
        acc[ih * 4 + t][j] = __builtin_amdgcn_mfma_f32_16x16x32_bf16(
            afrag[t], bfrag[j], acc[ih * 4 + t][j], 0, 0, 0);
    __builtin_amdgcn_s_setprio(0);
  };

  const int NT = K >> 6;   // K-tiles (=16 here); requires NT >= 2

  // ---- prologue: tile0 (4 slabs) + tile1 (3 slabs); A-kk1(1) comes at (0,p1)
  stage(Bslab(0, 0), Bg);
  stage(Aslab(0, 0), Ag);
  stage(Bslab(0, 1), Bg + 32);
  stage(Aslab(0, 1), Ag + 32);
  asm volatile("s_waitcnt vmcnt(4)" ::: "memory");
  stage(Bslab(1, 0), Bg + 64);
  stage(Aslab(1, 0), Ag + 64);
  stage(Bslab(1, 1), Bg + 96);
  asm volatile("s_waitcnt vmcnt(6)" ::: "memory");
  __builtin_amdgcn_s_barrier();

#pragma unroll 1
  for (int kt = 0; kt < NT; ++kt) {
    const int buf = kt & 1;
    // ---------- phase 1: kk0, m 0..3 (reads B kk0) ----------
#pragma unroll
    for (int j = 0; j < 4; j++) bfrag[j] = ldB(buf, 0, j);
#pragma unroll
    for (int t = 0; t < 4; t++) afrag[t] = ldA(buf, 0, t);
    if (kt + 1 < NT) stage(Aslab(buf ^ 1, 1), Ag + (size_t)(kt + 1) * 64 + 32);
    __builtin_amdgcn_s_barrier();
    asm volatile("s_waitcnt lgkmcnt(0)" ::: "memory");
    mfma16(0);
    __builtin_amdgcn_s_barrier();
    // ---------- phase 2: kk0, m 4..7 (B reused in regs) ----------
#pragma unroll
    for (int t = 0; t < 4; t++) afrag[t] = ldA(buf, 0, 4 + t);
    if (kt + 2 < NT) stage(Bslab(buf, 0), Bg + (size_t)(kt + 2) * 64);
    __builtin_amdgcn_s_barrier();
    asm volatile("s_waitcnt lgkmcnt(0)" ::: "memory");
    mfma16(1);
    __builtin_amdgcn_s_barrier();
    // ---------- phase 3: kk1, m 0..3 (reads B kk1) ----------
#pragma unroll
    for (int j = 0; j < 4; j++) bfrag[j] = ldB(buf, 1, j);
#pragma unroll
    for (int t = 0; t < 4; t++) afrag[t] = ldA(buf, 1, t);
    if (kt + 2 < NT) stage(Aslab(buf, 0), Ag + (size_t)(kt + 2) * 64);
    __builtin_amdgcn_s_barrier();
    asm volatile("s_waitcnt lgkmcnt(0)" ::: "memory");
    mfma16(0);
    __builtin_amdgcn_s_barrier();
    // ---------- phase 4: kk1, m 4..7; counted vmcnt ----------
#pragma unroll
    for (int t = 0; t < 4; t++) afrag[t] = ldA(buf, 1, 4 + t);
    if (kt + 2 < NT) {
      stage(Bslab(buf, 1), Bg + (size_t)(kt + 2) * 64 + 32);
      asm volatile("s_waitcnt vmcnt(6)" ::: "memory");
    } else if (kt + 1 < NT) {
      asm volatile("s_waitcnt vmcnt(0)" ::: "memory");   // drain last stage
    }
    __builtin_amdgcn_s_barrier();
    asm volatile("s_waitcnt lgkmcnt(0)" ::: "memory");
    mfma16(1);
    __builtin_amdgcn_s_barrier();
  }

  // ---------------- Epilogue -----------------------------------------------
  // C/D layout: row = quad*4 + reg, col = lane&15.
  if (MODE == 0 && bn >= 2048) {
    // v-block: all 256 output cols map to v (bn multiple of 256 >= 2048).
    // LDS transpose in two 128-col (m) passes; tile [256 n][136 pad] ushort.
    const int bb = bm >> 12;
    const int n1b = bn & 1023;           // + row < 1024, no wrap
    const int sb  = bm & 4095;
#pragma unroll 1
    for (int p = 0; p < 2; p++) {
      __syncthreads();
      if (wr == p) {
#pragma unroll
        for (int i = 0; i < 8; i++)
#pragma unroll
          for (int j = 0; j < 4; j++)
#pragma unroll
            for (int r = 0; r < 4; r++)
              SH[(wc * 64 + j * 16 + l16) * 136 + i * 16 + quad * 4 + r] =
                  f2b(acc[i][j][r]);
      }
      __syncthreads();
#pragma unroll
      for (int it = 0; it < 8; it++) {
        const int row = it * 32 + (tid >> 4);          // n_local 0..255
        const int n1 = n1b + row;
        const int dh = n1 & 63, hh = n1 >> 6;
        const int s = sb + p * 128 + (tid & 15) * 8;
        uint4 val = *(const uint4*)&SH[row * 136 + (tid & 15) * 8];
        *(uint4*)&O2[(((size_t)bb * HH + hh) * DHH + dh) * SS + s] = val;
      }
    }
  } else {
#pragma unroll
    for (int i = 0; i < 8; i++) {
#pragma unroll
      for (int j = 0; j < 4; j++) {
#pragma unroll
        for (int r = 0; r < 4; r++) {
          int m = bm + wr * 128 + i * 16 + quad * 4 + r;
          int n = bn + wc * 64 + j * 16 + l16;
          float av = acc[i][j][r];
          if (MODE == 0) {
            int n1 = n & 1023;
            int h = n1 >> 6, dh = n1 & 63;
            int b = m >> 12, s = m & 4095;
            if (n < 1024) {
              O0[(((size_t)b * HH + h) * SS + s) * DHH + dh] = f2b(av * QSCALE);
            } else {
              O1[(((size_t)b * HH + h) * SS + s) * DHH + dh] = f2b(av);
            }
          } else {
            Of[(size_t)m * DD + n] = av;   // fp32 output
          }
        }
      }
    }
  }
}

// ---------------------------------------------------------------------------
// Attention v3: barrier-free, wave-independent, software-pipelined.
// (unchanged — verified in rounds 1/3)
// ---------------------------------------------------------------------------
__global__ __launch_bounds__(256, 2) void attn_kernel(
    const ushort_t* __restrict__ q, const ushort_t* __restrict__ k,
    const ushort_t* __restrict__ vT, ushort_t* __restrict__ out) {
  const int blk = blockIdx.x;
  const int h   = blockIdx.y;
  const int b   = blockIdx.z;
  const int tid  = threadIdx.x;
  const int lane = tid & 63;
  const int w    = tid >> 6;
  const int quad = lane >> 4;
  const int l16  = lane & 15;

  const size_t bh = ((size_t)b * HH + h) * SS * DHH;
  const ushort_t* qb  = q + bh;
  const ushort_t* kb  = k + bh;
  const ushort_t* vtb = vT + bh;   // layout [dh][s], row stride SS

  __shared__ __align__(16) ushort_t Ps[4][64 * 64];   // per-wave P tiles
  ushort_t* Pw = &Ps[w][0];

  const int q0 = blk * WW + w * 64;

  // P-tile element offsets, layout: elem(row,col) = (col>>3)*512 + row*8 + (col&7)
  const int wbase = ((l16 >> 3) << 9) + (quad << 5) + (l16 & 7);  // write: +nt*1024+mt*128+r*8
  const int rbase = (quad << 9) + (l16 << 3);                     // read:  +(ll>>3)*512+mt*128

  // Q fragments (A-operand: m = lane&15, k = x*32 + quad*8 + j)
  s16x8 aq[4][2];
#pragma unroll
  for (int mt = 0; mt < 4; mt++)
#pragma unroll
    for (int x = 0; x < 2; x++)
      aq[mt][x] = *(const s16x8*)&qb[(size_t)(q0 + mt * 16 + l16) * DHH + x * 32 + quad * 8];

  f32x4 oacc[4][4] = {};
  f32x4 rsacc[4] = {};

  s16x8 vone;
#pragma unroll
  for (int j = 0; j < 8; j++) vone[j] = (short)0x3F80;   // bf16 1.0

  s16x8 bk[4][2];   // K fragments (current / prefetched next chunk)
  s16x8 bv[4][2];   // V^T fragments (current chunk)

  auto LOADK = [&](int j0s) {
    const ushort_t* kc = kb + (size_t)j0s * DHH;
#pragma unroll
    for (int nt = 0; nt < 4; nt++)
#pragma unroll
      for (int x = 0; x < 2; x++)
        bk[nt][x] = *(const s16x8*)&kc[(nt * 16 + l16) * DHH + x * 32 + quad * 8];
  };
  auto LOADV = [&](int j0s) {
    const ushort_t* vc = vtb + j0s;
#pragma unroll
    for (int dt = 0; dt < 4; dt++)
#pragma unroll
      for (int x = 0; x < 2; x++)
        bv[dt][x] = *(const s16x8*)&vc[(size_t)(dt * 16 + l16) * SS + x * 32 + quad * 8];
  };

  const int jlo = (q0 - (int)WW < (int)GG) ? (int)GG : (q0 - (int)WW);
  int jhi = q0 + (int)WW;
  if (jhi > SS - 64) jhi = SS - 64;

  int j0  = jlo;
  int j0u = __builtin_amdgcn_readfirstlane(j0);
  LOADK(j0u);

  bool last = false;
  while (!last) {
    int jn = j0 + 64;
    if (j0 == 0) { last = true; jn = 0; }
    else if (jn > jhi) jn = 0;               // wrap to the global chunk

    LOADV(j0u);                               // issued early; needed in PV

    const int dlt = j0 - q0;
    const bool needmask = (j0 != 0) && (dlt < -193 || dlt > 193);

    // --- QK^T + exp2 + P-write (per-wave LDS, immediate-offset addressing)
#pragma unroll
    for (int nt = 0; nt < 4; nt++) {
      const int j = j0 + nt * 16 + l16;
#pragma unroll
      for (int mt = 0; mt < 4; mt++) {
        f32x4 s4 = {0.f, 0.f, 0.f, 0.f};
        s4 = __builtin_amdgcn_mfma_f32_16x16x32_bf16(aq[mt][0], bk[nt][0], s4, 0, 0, 0);
        s4 = __builtin_amdgcn_mfma_f32_16x16x32_bf16(aq[mt][1], bk[nt][1], s4, 0, 0, 0);
#pragma unroll
        for (int r = 0; r < 4; r++) {
          float p;
          if (needmask) {
            int i = q0 + mt * 16 + quad * 4 + r;
            int d = j - i;
            p = (d <= (int)WW && d >= -(int)WW) ? exp2f_fast(s4[r]) : 0.0f;
          } else {
            p = exp2f_fast(s4[r]);
          }
          Pw[wbase + nt * 1024 + mt * 128 + r * 8] = f2b1(p);
        }
      }
    }

    // --- prefetch next chunk's K while exp/P/PV run
    int jnu = __builtin_amdgcn_readfirstlane(jn);
    if (!last) LOADK(jnu);

    // --- PV + ones-MFMA row sums
    __builtin_amdgcn_s_setprio(1);
#pragma unroll
    for (int ll = 0; ll < 64; ll += 32) {
      s16x8 ap[4];
#pragma unroll
      for (int mt = 0; mt < 4; mt++)
        ap[mt] = *(const s16x8*)&Pw[rbase + (ll >> 3) * 512 + mt * 128];
#pragma unroll
      for (int mt = 0; mt < 4; mt++) {
        rsacc[mt] = __builtin_amdgcn_mfma_f32_16x16x32_bf16(ap[mt], vone, rsacc[mt], 0, 0, 0);
#pragma unroll
        for (int dt = 0; dt < 4; dt++)
          oacc[mt][dt] = __builtin_amdgcn_mfma_f32_16x16x32_bf16(ap[mt], bv[dt][ll >> 5], oacc[mt][dt], 0, 0, 0);
      }
    }
    __builtin_amdgcn_s_setprio(0);

    j0 = jn; j0u = jnu;
  }

  // Normalize + store (rsacc C-layout matches oacc rows: quad*4+r).
#pragma unroll
  for (int mt = 0; mt < 4; mt++) {
#pragma unroll
    for (int r = 0; r < 4; r++) {
      float inv = __builtin_amdgcn_rcpf(rsacc[mt][r]);
      int srow2 = q0 + mt * 16 + quad * 4 + r;
      size_t orow = ((size_t)b * SS + srow2) * DD + h * DHH;
#pragma unroll
      for (int dt = 0; dt < 4; dt++)
        out[orow + dt * 16 + l16] = f2b1(oacc[mt][dt][r] * inv);
    }
  }
}

// ---------------------------------------------------------------------------
extern "C" void kernel_launch(void* const* d_in, const int* in_sizes, int n_in,
                              void* d_out, int out_size, void* d_ws, size_t ws_size,
                              hipStream_t stream) {
  const float *x, *Wq, *Wk, *Wv, *Wo;
  if (n_in == 5 && in_sizes[4] == 8388608) {   // alphabetical fallback
    Wk = (const float*)d_in[0]; Wo = (const float*)d_in[1];
    Wq = (const float*)d_in[2]; Wv = (const float*)d_in[3];
    x  = (const float*)d_in[4];
  } else {                                      // dict order (confirmed round 5/6)
    x  = (const float*)d_in[0]; Wq = (const float*)d_in[1];
    Wk = (const float*)d_in[2]; Wv = (const float*)d_in[3];
    Wo = (const float*)d_in[4];
  }
  float* out = (float*)d_out;   // fp32 output (confirmed round 6)

  // Workspace (72 MiB, proven available):
  // [WqT|WkT|WvT] 6MiB | WoT 2MiB | q 16MiB | k 16MiB | vT 16MiB | attn/xb 16MiB
  // xb (bf16 x) shares the attn slot: consumed by gemm<0> before attn writes.
  char* ws = (char*)d_ws;
  ushort_t* wqkvT = (ushort_t*)(ws);
  ushort_t* woT   = (ushort_t*)(ws + 6291456);
  ushort_t* qbuf  = (ushort_t*)(ws + 8388608);
  ushort_t* kbuf  = (ushort_t*)(ws + 8388608 + 16777216);
  ushort_t* vbuf  = (ushort_t*)(ws + 8388608 + 2 * 16777216);
  ushort_t* attn  = (ushort_t*)(ws + 8388608 + 3 * 16777216);
  ushort_t* xb    = attn;   // alias, lifetime-disjoint

  xcast<<<dim3(4096), 256, 0, stream>>>(x, xb);
  transpose_w<<<dim3(16, 16, 4), 256, 0, stream>>>(Wq, Wk, Wv, Wo, wqkvT);
  gemm256<0><<<dim3(32, 12), 512, 0, stream>>>(xb, wqkvT, qbuf, kbuf, vbuf, nullptr, 1024);
  attn_kernel<<<dim3(NBLK, HH, BB), 256, 0, stream>>>(qbuf, kbuf, vbuf, attn);
  gemm256<1><<<dim3(32, 4), 512, 0, stream>>>(attn, woT, nullptr, nullptr, nullptr, out, 1024);
}

// Round 5
// 245.823 us; speedup vs baseline: 1.1095x; 1.0003x over previous
//
#include <hip/hip_runtime.h>

// Problem constants
#define BB   2
#define SS   4096
#define DD   1024
#define HH   16
#define DHH  64
#define WW   256
#define GG   64
#define NBLK 16    // S/W

typedef unsigned short ushort_t;
typedef short  s16x8 __attribute__((ext_vector_type(8)));
typedef float  f32x4 __attribute__((ext_vector_type(4)));

// 0.125 * log2(e): folded into q at QKV-GEMM epilogue time.
#define QSCALE 0.18033688011112042f

#define VMCNT(n) asm volatile("s_waitcnt vmcnt(" #n ")" ::: "memory")

// fp32 -> bf16 round-to-nearest-even, raw bits
__device__ __forceinline__ ushort_t f2b(float f) {
  unsigned int u = __builtin_bit_cast(unsigned int, f);
  unsigned int r = (u + 0x7fffu + ((u >> 16) & 1u)) >> 16;
  return (ushort_t)r;
}

// single-op fp32 -> bf16 (RNE) via v_cvt_pk_bf16_f32, low half used
__device__ __forceinline__ ushort_t f2b1(float f) {
  unsigned int r;
  asm("v_cvt_pk_bf16_f32 %0, %1, %2" : "=v"(r) : "v"(f), "v"(f));
  return (ushort_t)r;
}

__device__ __forceinline__ float exp2f_fast(float x) {
  return __builtin_amdgcn_exp2f(x);
}

// Async 16B global->LDS DMA. LDS dst must be wave-uniform base + lane*16.
__device__ __forceinline__ void gld16(const void* g, void* l) {
  __builtin_amdgcn_global_load_lds(
      (const __attribute__((address_space(1))) void*)g,
      (__attribute__((address_space(3))) void*)l, 16, 0, 0);
}

// ---------------------------------------------------------------------------
// x (fp32) -> bf16, flat. 4096 blocks x 256 thr x 8 elems.
// ---------------------------------------------------------------------------
__global__ __launch_bounds__(256) void xcast(
    const float* __restrict__ x, ushort_t* __restrict__ xb) {
  size_t i = ((size_t)blockIdx.x * 256 + threadIdx.x) * 8;
  float4 f0 = *(const float4*)&x[i];
  float4 f1 = *(const float4*)&x[i + 4];
  ushort_t t[8];
  t[0] = f2b(f0.x); t[1] = f2b(f0.y); t[2] = f2b(f0.z); t[3] = f2b(f0.w);
  t[4] = f2b(f1.x); t[5] = f2b(f1.y); t[6] = f2b(f1.z); t[7] = f2b(f1.w);
  *(uint4*)&xb[i] = *(const uint4*)t;
}

// ---------------------------------------------------------------------------
// Transpose + fp32->bf16 the four weight matrices into (n,k) bf16 layout.
// ---------------------------------------------------------------------------
__global__ __launch_bounds__(256) void transpose_w(
    const float* __restrict__ Wq, const float* __restrict__ Wk,
    const float* __restrict__ Wv, const float* __restrict__ Wo,
    ushort_t* __restrict__ outBase) {
  const float* src = (blockIdx.z == 0) ? Wq : (blockIdx.z == 1) ? Wk
                    : (blockIdx.z == 2) ? Wv : Wo;
  ushort_t* dst = outBase + (size_t)blockIdx.z * (1024 * 1024);
  __shared__ __align__(16) ushort_t t[64][72];
  const int tid = threadIdx.x;
  const int bx = blockIdx.x * 64, by = blockIdx.y * 64;
  const int c4 = (tid & 15) * 4;
  const int r16 = tid >> 4;
  for (int rr = r16; rr < 64; rr += 16) {
    float4 f = *(const float4*)&src[(size_t)(by + rr) * 1024 + bx + c4];
    t[c4 + 0][rr] = f2b(f.x);
    t[c4 + 1][rr] = f2b(f.y);
    t[c4 + 2][rr] = f2b(f.z);
    t[c4 + 3][rr] = f2b(f.w);
  }
  __syncthreads();
  const int sr = tid >> 3;
  const int sc = (tid & 7) * 8;
  for (int rr = sr; rr < 64; rr += 32) {
    *(uint4*)&dst[(size_t)(bx + rr) * 1024 + by + sc] = *(const uint4*)&t[rr][sc];
  }
}

// ---------------------------------------------------------------------------
// GEMM v2: BM=128, BN=WN*64, BK=32, 4-deep rotating LDS buffers, 1 phase per
// K-step (uniform shape): {reads (4A + WN B) | stage(s+3) (1 + LB gld16) |
// vmcnt(2*(1+LB)) | barrier | lgkmcnt(0) | setprio + 4*WN MFMA | barrier}.
//   - Ledger: stage(s+3) issued at s; vmcnt(2*(1+LB)) allows stages {s+2,s+3}
//     outstanding -> stage(s+1) retired before its reads at s+1 (post-BAR2).
//     Tail: s+3==NT -> vmcnt(1+LB); s+2==NT -> vmcnt(0); s==NT-1 none.
//   - WAR: stage target (s+3)&3 last read at phase s-1; every wave executed
//     lgkmcnt(0) before BAR2(s-1); stage issued after -> safe.
//   - Grids: MODE0 (64,8)=512 blocks = 2 exact CU rounds (no quantization);
//     MODE1 (64,4)=256 blocks = 1 round (was 128 = half machine idle).
//   - LDS: MODE0 128 KiB, MODE1 96 KiB. VGPR ~160/130 (cap 256, no spill).
//   - Same chunk-XOR swizzle (inverse-swizzled source, swizzled read),
//     same 2-D XCD super-tile swizzle (CW=8, gridDim.x=64).
// MODE 0 (WN=6): N=3072 QKV; q,k head-split (B,H,S,DH), q pre-scaled;
//                v TRANSPOSED (B,H,DH,S).
// MODE 1 (WN=4): fp32 row-major C to Of.
// ---------------------------------------------------------------------------
template <int MODE, int WN>
__global__ __launch_bounds__(512, 2) void gemmk(
    const ushort_t* __restrict__ A, const ushort_t* __restrict__ Bt,
    ushort_t* __restrict__ O0, ushort_t* __restrict__ O1,
    ushort_t* __restrict__ O2, float* __restrict__ Of, int K) {
  constexpr int BN    = WN * 64;
  constexpr int LB    = BN / 128;          // B gld16 passes per stage (3 or 2)
  constexpr int ASLAB = 128 * 32;          // ushorts (8 KiB)
  constexpr int BSLAB = BN * 32;           // ushorts (24 or 16 KiB)
  __shared__ __align__(16) ushort_t SH[4 * ASLAB + 4 * BSLAB];

  const int tid  = threadIdx.x;        // 0..511
  const int lane = tid & 63;
  const int w    = tid >> 6;           // 0..7
  const int quad = lane >> 4;
  const int l16  = lane & 15;
  const int wr   = w >> 2;             // 0..1 (M): 64 rows each
  const int wc   = w & 3;              // 0..3 (N): WN*16 cols each

  // 2-D super-tile XCD swizzle (gridDim.x == 64, CW = 8)
  const int id  = blockIdx.x + (gridDim.x * blockIdx.y);
  const int xcd = id & 7;
  const int seq = id >> 3;
  const int nx  = (xcd << 3) + (seq & 7);
  const int ny  = seq >> 3;
  const int bm  = nx * 128;
  const int bn  = ny * BN;

  // Staging: thread covers LDS row srow (+p*128 for B), chunk tid&3 (linear
  // dest); global source chunk inverse-swizzled so reads XOR-deswizzle.
  const int srow = tid >> 2;                        // 0..127
  const int sch  = (tid & 3) ^ ((srow >> 1) & 3);
  const ushort_t* Ag = A + (size_t)(bm + srow) * K + sch * 8;
  const ushort_t* Bg = Bt + (size_t)(bn + srow) * K + sch * 8;

  // Fragment-read swizzle: chunk = quad ^ ((row>>1)&3) = quad ^ ((l16>>1)&3).
  const int chofs = ((quad ^ ((l16 >> 1) & 3)) << 3);

  f32x4 acc[4][WN] = {};

  const int NT = K >> 5;   // 32 K-steps

  // ---- prologue: stage s = 0,1,2 into buffers 0,1,2
#pragma unroll
  for (int s0 = 0; s0 < 3; s0++) {
    gld16(Ag + (size_t)s0 * 32, &SH[s0 * ASLAB + tid * 8]);
#pragma unroll
    for (int p = 0; p < LB; p++)
      gld16(Bg + (size_t)(p * 128) * K + (size_t)s0 * 32,
            &SH[4 * ASLAB + s0 * BSLAB + p * 4096 + tid * 8]);
  }
  if constexpr (WN == 6) VMCNT(8); else VMCNT(6);   // s=0 landed
  __builtin_amdgcn_s_barrier();

#pragma unroll 1
  for (int s = 0; s < NT; ++s) {
    const int buf = s & 3;
    const ushort_t* Ab = &SH[buf * ASLAB];
    const ushort_t* Bb = &SH[4 * ASLAB + buf * BSLAB];
    s16x8 afrag[4], bfrag[WN];
#pragma unroll
    for (int j = 0; j < WN; j++)
      bfrag[j] = *(const s16x8*)&Bb[(wc * (WN * 16) + j * 16 + l16) * 32 + chofs];
#pragma unroll
    for (int t = 0; t < 4; t++)
      afrag[t] = *(const s16x8*)&Ab[(wr * 64 + t * 16 + l16) * 32 + chofs];

    if (s + 3 < NT) {
      const int sn = s + 3;
      ushort_t* An = &SH[(sn & 3) * ASLAB];
      ushort_t* Bn = &SH[4 * ASLAB + (sn & 3) * BSLAB];
      gld16(Ag + (size_t)sn * 32, &An[tid * 8]);
#pragma unroll
      for (int p = 0; p < LB; p++)
        gld16(Bg + (size_t)(p * 128) * K + (size_t)sn * 32,
              &Bn[p * 4096 + tid * 8]);
      if constexpr (WN == 6) VMCNT(8); else VMCNT(6);
    } else if (s + 3 == NT) {
      if constexpr (WN == 6) VMCNT(4); else VMCNT(3);
    } else if (s + 2 == NT) {
      VMCNT(0);
    }
    __builtin_amdgcn_s_barrier();
    asm volatile("s_waitcnt lgkmcnt(0)" ::: "memory");
    __builtin_amdgcn_s_setprio(1);
#pragma unroll
    for (int t = 0; t < 4; t++)
#pragma unroll
      for (int j = 0; j < WN; j++)
        acc[t][j] = __builtin_amdgcn_mfma_f32_16x16x32_bf16(
            afrag[t], bfrag[j], acc[t][j], 0, 0, 0);
    __builtin_amdgcn_s_setprio(0);
    __builtin_amdgcn_s_barrier();
  }

  // Epilogue. C/D layout: row = quad*4 + reg, col = lane&15.
#pragma unroll
  for (int i = 0; i < 4; i++) {
#pragma unroll
    for (int j = 0; j < WN; j++) {
#pragma unroll
      for (int r = 0; r < 4; r++) {
        int m = bm + wr * 64 + i * 16 + quad * 4 + r;
        int n = bn + wc * (WN * 16) + j * 16 + l16;
        float av = acc[i][j][r];
        if (MODE == 0) {
          int n1 = n & 1023;
          int h = n1 >> 6, dh = n1 & 63;
          int b = m >> 12, s = m & 4095;
          if (n < 1024) {
            O0[(((size_t)b * HH + h) * SS + s) * DHH + dh] = f2b(av * QSCALE);  // q
          } else if (n < 2048) {
            O1[(((size_t)b * HH + h) * SS + s) * DHH + dh] = f2b(av);           // k
          } else {
            O2[(((size_t)b * HH + h) * DHH + dh) * SS + s] = f2b(av);           // v^T
          }
        } else {
          Of[(size_t)m * DD + n] = av;   // fp32 output
        }
      }
    }
  }
}

// ---------------------------------------------------------------------------
// Attention v3: barrier-free, wave-independent, software-pipelined.
// (unchanged — verified in rounds 1/3/4)
// ---------------------------------------------------------------------------
__global__ __launch_bounds__(256, 2) void attn_kernel(
    const ushort_t* __restrict__ q, const ushort_t* __restrict__ k,
    const ushort_t* __restrict__ vT, ushort_t* __restrict__ out) {
  const int blk = blockIdx.x;
  const int h   = blockIdx.y;
  const int b   = blockIdx.z;
  const int tid  = threadIdx.x;
  const int lane = tid & 63;
  const int w    = tid >> 6;
  const int quad = lane >> 4;
  const int l16  = lane & 15;

  const size_t bh = ((size_t)b * HH + h) * SS * DHH;
  const ushort_t* qb  = q + bh;
  const ushort_t* kb  = k + bh;
  const ushort_t* vtb = vT + bh;   // layout [dh][s], row stride SS

  __shared__ __align__(16) ushort_t Ps[4][64 * 64];   // per-wave P tiles
  ushort_t* Pw = &Ps[w][0];

  const int q0 = blk * WW + w * 64;

  const int wbase = ((l16 >> 3) << 9) + (quad << 5) + (l16 & 7);
  const int rbase = (quad << 9) + (l16 << 3);

  s16x8 aq[4][2];
#pragma unroll
  for (int mt = 0; mt < 4; mt++)
#pragma unroll
    for (int x = 0; x < 2; x++)
      aq[mt][x] = *(const s16x8*)&qb[(size_t)(q0 + mt * 16 + l16) * DHH + x * 32 + quad * 8];

  f32x4 oacc[4][4] = {};
  f32x4 rsacc[4] = {};

  s16x8 vone;
#pragma unroll
  for (int j = 0; j < 8; j++) vone[j] = (short)0x3F80;   // bf16 1.0

  s16x8 bk[4][2];
  s16x8 bv[4][2];

  auto LOADK = [&](int j0s) {
    const ushort_t* kc = kb + (size_t)j0s * DHH;
#pragma unroll
    for (int nt = 0; nt < 4; nt++)
#pragma unroll
      for (int x = 0; x < 2; x++)
        bk[nt][x] = *(const s16x8*)&kc[(nt * 16 + l16) * DHH + x * 32 + quad * 8];
  };
  auto LOADV = [&](int j0s) {
    const ushort_t* vc = vtb + j0s;
#pragma unroll
    for (int dt = 0; dt < 4; dt++)
#pragma unroll
      for (int x = 0; x < 2; x++)
        bv[dt][x] = *(const s16x8*)&vc[(size_t)(dt * 16 + l16) * SS + x * 32 + quad * 8];
  };

  const int jlo = (q0 - (int)WW < (int)GG) ? (int)GG : (q0 - (int)WW);
  int jhi = q0 + (int)WW;
  if (jhi > SS - 64) jhi = SS - 64;

  int j0  = jlo;
  int j0u = __builtin_amdgcn_readfirstlane(j0);
  LOADK(j0u);

  bool last = false;
  while (!last) {
    int jn = j0 + 64;
    if (j0 == 0) { last = true; jn = 0; }
    else if (jn > jhi) jn = 0;               // wrap to the global chunk

    LOADV(j0u);

    const int dlt = j0 - q0;
    const bool needmask = (j0 != 0) && (dlt < -193 || dlt > 193);

#pragma unroll
    for (int nt = 0; nt < 4; nt++) {
      const int j = j0 + nt * 16 + l16;
#pragma unroll
      for (int mt = 0; mt < 4; mt++) {
        f32x4 s4 = {0.f, 0.f, 0.f, 0.f};
        s4 = __builtin_amdgcn_mfma_f32_16x16x32_bf16(aq[mt][0], bk[nt][0], s4, 0, 0, 0);
        s4 = __builtin_amdgcn_mfma_f32_16x16x32_bf16(aq[mt][1], bk[nt][1], s4, 0, 0, 0);
#pragma unroll
        for (int r = 0; r < 4; r++) {
          float p;
          if (needmask) {
            int i = q0 + mt * 16 + quad * 4 + r;
            int d = j - i;
            p = (d <= (int)WW && d >= -(int)WW) ? exp2f_fast(s4[r]) : 0.0f;
          } else {
            p = exp2f_fast(s4[r]);
          }
          Pw[wbase + nt * 1024 + mt * 128 + r * 8] = f2b1(p);
        }
      }
    }

    int jnu = __builtin_amdgcn_readfirstlane(jn);
    if (!last) LOADK(jnu);

    __builtin_amdgcn_s_setprio(1);
#pragma unroll
    for (int ll = 0; ll < 64; ll += 32) {
      s16x8 ap[4];
#pragma unroll
      for (int mt = 0; mt < 4; mt++)
        ap[mt] = *(const s16x8*)&Pw[rbase + (ll >> 3) * 512 + mt * 128];
#pragma unroll
      for (int mt = 0; mt < 4; mt++) {
        rsacc[mt] = __builtin_amdgcn_mfma_f32_16x16x32_bf16(ap[mt], vone, rsacc[mt], 0, 0, 0);
#pragma unroll
        for (int dt = 0; dt < 4; dt++)
          oacc[mt][dt] = __builtin_amdgcn_mfma_f32_16x16x32_bf16(ap[mt], bv[dt][ll >> 5], oacc[mt][dt], 0, 0, 0);
      }
    }
    __builtin_amdgcn_s_setprio(0);

    j0 = jn; j0u = jnu;
  }

#pragma unroll
  for (int mt = 0; mt < 4; mt++) {
#pragma unroll
    for (int r = 0; r < 4; r++) {
      float inv = __builtin_amdgcn_rcpf(rsacc[mt][r]);
      int srow2 = q0 + mt * 16 + quad * 4 + r;
      size_t orow = ((size_t)b * SS + srow2) * DD + h * DHH;
#pragma unroll
      for (int dt = 0; dt < 4; dt++)
        out[orow + dt * 16 + l16] = f2b1(oacc[mt][dt][r] * inv);
    }
  }
}

// ---------------------------------------------------------------------------
extern "C" void kernel_launch(void* const* d_in, const int* in_sizes, int n_in,
                              void* d_out, int out_size, void* d_ws, size_t ws_size,
                              hipStream_t stream) {
  const float *x, *Wq, *Wk, *Wv, *Wo;
  if (n_in == 5 && in_sizes[4] == 8388608) {   // alphabetical fallback
    Wk = (const float*)d_in[0]; Wo = (const float*)d_in[1];
    Wq = (const float*)d_in[2]; Wv = (const float*)d_in[3];
    x  = (const float*)d_in[4];
  } else {                                      // dict order (confirmed round 5/6)
    x  = (const float*)d_in[0]; Wq = (const float*)d_in[1];
    Wk = (const float*)d_in[2]; Wv = (const float*)d_in[3];
    Wo = (const float*)d_in[4];
  }
  float* out = (float*)d_out;   // fp32 output (confirmed round 6)

  // Workspace (72 MiB, proven available):
  // [WqT|WkT|WvT] 6MiB | WoT 2MiB | q 16MiB | k 16MiB | vT 16MiB | attn/xb 16MiB
  char* ws = (char*)d_ws;
  ushort_t* wqkvT = (ushort_t*)(ws);
  ushort_t* woT   = (ushort_t*)(ws + 6291456);
  ushort_t* qbuf  = (ushort_t*)(ws + 8388608);
  ushort_t* kbuf  = (ushort_t*)(ws + 8388608 + 16777216);
  ushort_t* vbuf  = (ushort_t*)(ws + 8388608 + 2 * 16777216);
  ushort_t* attn  = (ushort_t*)(ws + 8388608 + 3 * 16777216);
  ushort_t* xb    = attn;   // alias, lifetime-disjoint

  xcast<<<dim3(4096), 256, 0, stream>>>(x, xb);
  transpose_w<<<dim3(16, 16, 4), 256, 0, stream>>>(Wq, Wk, Wv, Wo, wqkvT);
  gemmk<0, 6><<<dim3(64, 8), 512, 0, stream>>>(xb, wqkvT, qbuf, kbuf, vbuf, nullptr, 1024);
  attn_kernel<<<dim3(NBLK, HH, BB), 256, 0, stream>>>(qbuf, kbuf, vbuf, attn);
  gemmk<1, 4><<<dim3(64, 4), 512, 0, stream>>>(attn, woT, nullptr, nullptr, nullptr, out, 1024);
}

// Round 6
// 239.108 us; speedup vs baseline: 1.1407x; 1.0281x over previous
//
#include <hip/hip_runtime.h>

// Problem constants
#define BB   2
#define SS   4096
#define DD   1024
#define HH   16
#define DHH  64
#define WW   256
#define GG   64
#define NBLK 16    // S/W

typedef unsigned short ushort_t;
typedef short  s16x8 __attribute__((ext_vector_type(8)));
typedef float  f32x4 __attribute__((ext_vector_type(4)));

// 0.125 * log2(e): folded into q at QKV-GEMM epilogue time.
#define QSCALE 0.18033688011112042f

#define VMCNT(n) asm volatile("s_waitcnt vmcnt(" #n ")" ::: "memory")

// fp32 -> bf16 round-to-nearest-even, raw bits
__device__ __forceinline__ ushort_t f2b(float f) {
  unsigned int u = __builtin_bit_cast(unsigned int, f);
  unsigned int r = (u + 0x7fffu + ((u >> 16) & 1u)) >> 16;
  return (ushort_t)r;
}

// single-op fp32 -> bf16 (RNE) via v_cvt_pk_bf16_f32, low half used
__device__ __forceinline__ ushort_t f2b1(float f) {
  unsigned int r;
  asm("v_cvt_pk_bf16_f32 %0, %1, %2" : "=v"(r) : "v"(f), "v"(f));
  return (ushort_t)r;
}

__device__ __forceinline__ float exp2f_fast(float x) {
  return __builtin_amdgcn_exp2f(x);
}

// Async 16B global->LDS DMA. LDS dst must be wave-uniform base + lane*16.
__device__ __forceinline__ void gld16(const void* g, void* l) {
  __builtin_amdgcn_global_load_lds(
      (const __attribute__((address_space(1))) void*)g,
      (__attribute__((address_space(3))) void*)l, 16, 0, 0);
}

// ---------------------------------------------------------------------------
// x (fp32) -> bf16, flat. 4096 blocks x 256 thr x 8 elems.
// ---------------------------------------------------------------------------
__global__ __launch_bounds__(256) void xcast(
    const float* __restrict__ x, ushort_t* __restrict__ xb) {
  size_t i = ((size_t)blockIdx.x * 256 + threadIdx.x) * 8;
  float4 f0 = *(const float4*)&x[i];
  float4 f1 = *(const float4*)&x[i + 4];
  ushort_t t[8];
  t[0] = f2b(f0.x); t[1] = f2b(f0.y); t[2] = f2b(f0.z); t[3] = f2b(f0.w);
  t[4] = f2b(f1.x); t[5] = f2b(f1.y); t[6] = f2b(f1.z); t[7] = f2b(f1.w);
  *(uint4*)&xb[i] = *(const uint4*)t;
}

// ---------------------------------------------------------------------------
// Transpose + fp32->bf16 the four weight matrices into (n,k) bf16 layout.
// ---------------------------------------------------------------------------
__global__ __launch_bounds__(256) void transpose_w(
    const float* __restrict__ Wq, const float* __restrict__ Wk,
    const float* __restrict__ Wv, const float* __restrict__ Wo,
    ushort_t* __restrict__ outBase) {
  const float* src = (blockIdx.z == 0) ? Wq : (blockIdx.z == 1) ? Wk
                    : (blockIdx.z == 2) ? Wv : Wo;
  ushort_t* dst = outBase + (size_t)blockIdx.z * (1024 * 1024);
  __shared__ __align__(16) ushort_t t[64][72];
  const int tid = threadIdx.x;
  const int bx = blockIdx.x * 64, by = blockIdx.y * 64;
  const int c4 = (tid & 15) * 4;
  const int r16 = tid >> 4;
  for (int rr = r16; rr < 64; rr += 16) {
    float4 f = *(const float4*)&src[(size_t)(by + rr) * 1024 + bx + c4];
    t[c4 + 0][rr] = f2b(f.x);
    t[c4 + 1][rr] = f2b(f.y);
    t[c4 + 2][rr] = f2b(f.z);
    t[c4 + 3][rr] = f2b(f.w);
  }
  __syncthreads();
  const int sr = tid >> 3;
  const int sc = (tid & 7) * 8;
  for (int rr = sr; rr < 64; rr += 32) {
    *(uint4*)&dst[(size_t)(bx + rr) * 1024 + by + sc] = *(const uint4*)&t[rr][sc];
  }
}

// ---------------------------------------------------------------------------
// QKV GEMM: 256x256 tile, 8-phase pipelined schedule — EXACT round-4 kernel
// (best measured: 76.7 us, MfmaUtil 28%). 2-D super-tile XCD swizzle + v-block
// LDS-transpose epilogue. See round-4 comments for the vmcnt/slab ledger.
// ---------------------------------------------------------------------------
__global__ __launch_bounds__(512, 2) void gemm256(
    const ushort_t* __restrict__ A, const ushort_t* __restrict__ Bt,
    ushort_t* __restrict__ O0, ushort_t* __restrict__ O1,
    ushort_t* __restrict__ O2, float* __restrict__ Of, int K) {
  __shared__ __align__(16) ushort_t SH[65536];

  const int tid  = threadIdx.x;        // 0..511
  const int lane = tid & 63;
  const int w    = tid >> 6;           // 0..7
  const int quad = lane >> 4;          // 0..3
  const int l16  = lane & 15;
  const int wr   = w >> 2;             // 0..1  (M)
  const int wc   = w & 3;              // 0..3  (N)

  // 2-D super-tile XCD swizzle (gridDim.x must be 32)
  const int id  = blockIdx.x + (gridDim.x * blockIdx.y);
  const int xcd = id & 7;
  const int seq = id >> 3;
  const int nx  = (xcd << 2) + (seq & 3);
  const int ny  = seq >> 2;
  const int bm  = nx * 256;
  const int bn  = ny * 256;

  auto Aslab = [&](int buf, int kkh) -> ushort_t* {
    return &SH[(buf * 2 + kkh) * 8192];
  };
  auto Bslab = [&](int buf, int kkh) -> ushort_t* {
    return &SH[32768 + (buf * 2 + kkh) * 8192];
  };

  const int srow = tid >> 2;                        // 0..127
  const int sch  = (tid & 3) ^ ((srow >> 1) & 3);   // source 16B chunk in row
  const ushort_t* Ag = A + (size_t)(bm + srow) * K + sch * 8;
  const ushort_t* Bg = Bt + (size_t)(bn + srow) * K + sch * 8;

  const int chofs = ((quad ^ ((l16 >> 1) & 3)) << 3);

  auto stage = [&](ushort_t* slab, const ushort_t* g) {
    gld16(g, &slab[tid * 8]);
    gld16(g + (size_t)128 * K, &slab[4096 + tid * 8]);
  };

  f32x4 acc[8][4] = {};
  s16x8 afrag[4], bfrag[4];

  auto ldA = [&](int buf, int kkh, int i) {
    const int row = wr * 128 + i * 16 + l16;
    return *(const s16x8*)&Aslab(buf, kkh)[row * 32 + chofs];
  };
  auto ldB = [&](int buf, int kkh, int j) {
    const int row = wc * 64 + j * 16 + l16;
    return *(const s16x8*)&Bslab(buf, kkh)[row * 32 + chofs];
  };
  auto mfma16 = [&](int ih) {
    __builtin_amdgcn_s_setprio(1);
#pragma unroll
    for (int t = 0; t < 4; t++)
#pragma unroll
      for (int j = 0; j < 4; j++)
        acc[ih * 4 + t][j] = __builtin_amdgcn_mfma_f32_16x16x32_bf16(
            afrag[t], bfrag[j], acc[ih * 4 + t][j], 0, 0, 0);
    __builtin_amdgcn_s_setprio(0);
  };

  const int NT = K >> 6;

  stage(Bslab(0, 0), Bg);
  stage(Aslab(0, 0), Ag);
  stage(Bslab(0, 1), Bg + 32);
  stage(Aslab(0, 1), Ag + 32);
  VMCNT(4);
  stage(Bslab(1, 0), Bg + 64);
  stage(Aslab(1, 0), Ag + 64);
  stage(Bslab(1, 1), Bg + 96);
  VMCNT(6);
  __builtin_amdgcn_s_barrier();

#pragma unroll 1
  for (int kt = 0; kt < NT; ++kt) {
    const int buf = kt & 1;
    // phase 1: kk0, m 0..3
#pragma unroll
    for (int j = 0; j < 4; j++) bfrag[j] = ldB(buf, 0, j);
#pragma unroll
    for (int t = 0; t < 4; t++) afrag[t] = ldA(buf, 0, t);
    if (kt + 1 < NT) stage(Aslab(buf ^ 1, 1), Ag + (size_t)(kt + 1) * 64 + 32);
    __builtin_amdgcn_s_barrier();
    asm volatile("s_waitcnt lgkmcnt(0)" ::: "memory");
    mfma16(0);
    __builtin_amdgcn_s_barrier();
    // phase 2: kk0, m 4..7
#pragma unroll
    for (int t = 0; t < 4; t++) afrag[t] = ldA(buf, 0, 4 + t);
    if (kt + 2 < NT) stage(Bslab(buf, 0), Bg + (size_t)(kt + 2) * 64);
    __builtin_amdgcn_s_barrier();
    asm volatile("s_waitcnt lgkmcnt(0)" ::: "memory");
    mfma16(1);
    __builtin_amdgcn_s_barrier();
    // phase 3: kk1, m 0..3
#pragma unroll
    for (int j = 0; j < 4; j++) bfrag[j] = ldB(buf, 1, j);
#pragma unroll
    for (int t = 0; t < 4; t++) afrag[t] = ldA(buf, 1, t);
    if (kt + 2 < NT) stage(Aslab(buf, 0), Ag + (size_t)(kt + 2) * 64);
    __builtin_amdgcn_s_barrier();
    asm volatile("s_waitcnt lgkmcnt(0)" ::: "memory");
    mfma16(0);
    __builtin_amdgcn_s_barrier();
    // phase 4: kk1, m 4..7; counted vmcnt
#pragma unroll
    for (int t = 0; t < 4; t++) afrag[t] = ldA(buf, 1, 4 + t);
    if (kt + 2 < NT) {
      stage(Bslab(buf, 1), Bg + (size_t)(kt + 2) * 64 + 32);
      VMCNT(6);
    } else if (kt + 1 < NT) {
      VMCNT(0);
    }
    __builtin_amdgcn_s_barrier();
    asm volatile("s_waitcnt lgkmcnt(0)" ::: "memory");
    mfma16(1);
    __builtin_amdgcn_s_barrier();
  }

  // Epilogue. C/D layout: row = quad*4 + reg, col = lane&15.
  if (bn >= 2048) {
    // v-block: LDS transpose, coalesced 16B stores.
    const int bb = bm >> 12;
    const int n1b = bn & 1023;
    const int sb  = bm & 4095;
#pragma unroll 1
    for (int p = 0; p < 2; p++) {
      __syncthreads();
      if (wr == p) {
#pragma unroll
        for (int i = 0; i < 8; i++)
#pragma unroll
          for (int j = 0; j < 4; j++)
#pragma unroll
            for (int r = 0; r < 4; r++)
              SH[(wc * 64 + j * 16 + l16) * 136 + i * 16 + quad * 4 + r] =
                  f2b(acc[i][j][r]);
      }
      __syncthreads();
#pragma unroll
      for (int it = 0; it < 8; it++) {
        const int row = it * 32 + (tid >> 4);
        const int n1 = n1b + row;
        const int dh = n1 & 63, hh = n1 >> 6;
        const int s = sb + p * 128 + (tid & 15) * 8;
        uint4 val = *(const uint4*)&SH[row * 136 + (tid & 15) * 8];
        *(uint4*)&O2[(((size_t)bb * HH + hh) * DHH + dh) * SS + s] = val;
      }
    }
  } else {
#pragma unroll
    for (int i = 0; i < 8; i++) {
#pragma unroll
      for (int j = 0; j < 4; j++) {
#pragma unroll
        for (int r = 0; r < 4; r++) {
          int m = bm + wr * 128 + i * 16 + quad * 4 + r;
          int n = bn + wc * 64 + j * 16 + l16;
          float av = acc[i][j][r];
          int n1 = n & 1023;
          int h = n1 >> 6, dh = n1 & 63;
          int b = m >> 12, s = m & 4095;
          if (n < 1024) {
            O0[(((size_t)b * HH + h) * SS + s) * DHH + dh] = f2b(av * QSCALE);
          } else {
            O1[(((size_t)b * HH + h) * SS + s) * DHH + dh] = f2b(av);
          }
        }
      }
    }
  }
}

// ---------------------------------------------------------------------------
// Output-projection GEMM, decoupled-occupancy design:
//   128x128 tile, BK=32, double-buffered 32 KiB LDS, 256 threads (4 waves,
//   2Mx2N, wave tile 64x64, acc[4][4]=64 VGPR), __launch_bounds__(256,4)
//   caps VGPR at 128 -> 4 blocks/CU co-resident (LDS 32KB allows 5).
//   Rationale (round-5 post-mortem): staging delivery scales with blocks/CU
//   (r1: 4-5/CU -> 7.4 TB/s, no swizzle) x XCD locality (+~37%); per-phase
//   in-CU structure is secondary. Counted VMCNT(4) keeps next stage in
//   flight; barrier-uniform; WAR safe (reads of buf^1 complete before the
//   closing barrier of the prior phase; stage issued after it).
//   Grid (64,8) = 512 blocks = 2 exact resident rounds at 4/CU.
// C(M,N) = A(M,K) @ Bt(N,K)^T, bf16 in, fp32 out row-major.
// ---------------------------------------------------------------------------
__global__ __launch_bounds__(256, 4) void gemmk128(
    const ushort_t* __restrict__ A, const ushort_t* __restrict__ Bt,
    float* __restrict__ Of, int K) {
  __shared__ __align__(16) ushort_t As[2][128 * 32];
  __shared__ __align__(16) ushort_t Bs[2][128 * 32];

  const int tid  = threadIdx.x;        // 0..255
  const int lane = tid & 63;
  const int w    = tid >> 6;           // 0..3
  const int quad = lane >> 4;
  const int l16  = lane & 15;
  const int wr   = w >> 1;             // 0..1 (M)
  const int wc   = w & 1;              // 0..1 (N)

  // 2-D super-tile XCD swizzle (gridDim.x == 64)
  const int id  = blockIdx.x + (gridDim.x * blockIdx.y);
  const int xcd = id & 7;
  const int seq = id >> 3;
  const int nx  = (xcd << 3) + (seq & 7);
  const int ny  = seq >> 3;
  const int bm  = nx * 128;
  const int bn  = ny * 128;

  // Staging: 256 thr x 16B = 4KB/pass; slab 8KB -> 2 passes (rows 0..63,
  // 64..127). Linear LDS dest tid*16B; source chunk inverse-XOR-swizzled.
  const int srow = tid >> 2;                        // 0..63
  const int sch  = (tid & 3) ^ ((srow >> 1) & 3);
  const ushort_t* Ag = A + (size_t)(bm + srow) * K + sch * 8;
  const ushort_t* Bg = Bt + (size_t)(bn + srow) * K + sch * 8;
  const int sch2 = (tid & 3) ^ (((srow + 64) >> 1) & 3);
  const ushort_t* Ag2 = A + (size_t)(bm + srow + 64) * K + sch2 * 8;
  const ushort_t* Bg2 = Bt + (size_t)(bn + srow + 64) * K + sch2 * 8;

  const int chofs = ((quad ^ ((l16 >> 1) & 3)) << 3);

  auto stage = [&](int buf, int s) {
    gld16(Ag + (size_t)s * 32, &As[buf][tid * 8]);
    gld16(Ag2 + (size_t)s * 32, &As[buf][2048 + tid * 8]);
    gld16(Bg + (size_t)s * 32, &Bs[buf][tid * 8]);
    gld16(Bg2 + (size_t)s * 32, &Bs[buf][2048 + tid * 8]);
  };

  f32x4 acc[4][4] = {};

  const int NT = K >> 5;   // 32 K-steps

  stage(0, 0);
  VMCNT(0);
  __builtin_amdgcn_s_barrier();

#pragma unroll 1
  for (int s = 0; s < NT; ++s) {
    const int buf = s & 1;
    if (s + 1 < NT) {
      stage(buf ^ 1, s + 1);
      VMCNT(4);                      // stage(s) landed; stage(s+1) in flight
    } else {
      VMCNT(0);
    }
    __builtin_amdgcn_s_barrier();
    s16x8 afrag[4], bfrag[4];
#pragma unroll
    for (int t = 0; t < 4; t++)
      afrag[t] = *(const s16x8*)&As[buf][(wr * 64 + t * 16 + l16) * 32 + chofs];
#pragma unroll
    for (int j = 0; j < 4; j++)
      bfrag[j] = *(const s16x8*)&Bs[buf][(wc * 64 + j * 16 + l16) * 32 + chofs];
    asm volatile("s_waitcnt lgkmcnt(0)" ::: "memory");
    __builtin_amdgcn_s_setprio(1);
#pragma unroll
    for (int t = 0; t < 4; t++)
#pragma unroll
      for (int j = 0; j < 4; j++)
        acc[t][j] = __builtin_amdgcn_mfma_f32_16x16x32_bf16(
            afrag[t], bfrag[j], acc[t][j], 0, 0, 0);
    __builtin_amdgcn_s_setprio(0);
    __builtin_amdgcn_s_barrier();
  }

  // Epilogue: fp32 row-major. C/D: row = quad*4 + r, col = l16.
#pragma unroll
  for (int i = 0; i < 4; i++) {
#pragma unroll
    for (int j = 0; j < 4; j++) {
#pragma unroll
      for (int r = 0; r < 4; r++) {
        int m = bm + wr * 64 + i * 16 + quad * 4 + r;
        int n = bn + wc * 64 + j * 16 + l16;
        Of[(size_t)m * DD + n] = acc[i][j][r];
      }
    }
  }
}

// ---------------------------------------------------------------------------
// Attention v3: barrier-free, wave-independent, software-pipelined.
// (unchanged — verified in rounds 1/3/4/5)
// ---------------------------------------------------------------------------
__global__ __launch_bounds__(256, 2) void attn_kernel(
    const ushort_t* __restrict__ q, const ushort_t* __restrict__ k,
    const ushort_t* __restrict__ vT, ushort_t* __restrict__ out) {
  const int blk = blockIdx.x;
  const int h   = blockIdx.y;
  const int b   = blockIdx.z;
  const int tid  = threadIdx.x;
  const int lane = tid & 63;
  const int w    = tid >> 6;
  const int quad = lane >> 4;
  const int l16  = lane & 15;

  const size_t bh = ((size_t)b * HH + h) * SS * DHH;
  const ushort_t* qb  = q + bh;
  const ushort_t* kb  = k + bh;
  const ushort_t* vtb = vT + bh;   // layout [dh][s], row stride SS

  __shared__ __align__(16) ushort_t Ps[4][64 * 64];   // per-wave P tiles
  ushort_t* Pw = &Ps[w][0];

  const int q0 = blk * WW + w * 64;

  const int wbase = ((l16 >> 3) << 9) + (quad << 5) + (l16 & 7);
  const int rbase = (quad << 9) + (l16 << 3);

  s16x8 aq[4][2];
#pragma unroll
  for (int mt = 0; mt < 4; mt++)
#pragma unroll
    for (int x = 0; x < 2; x++)
      aq[mt][x] = *(const s16x8*)&qb[(size_t)(q0 + mt * 16 + l16) * DHH + x * 32 + quad * 8];

  f32x4 oacc[4][4] = {};
  f32x4 rsacc[4] = {};

  s16x8 vone;
#pragma unroll
  for (int j = 0; j < 8; j++) vone[j] = (short)0x3F80;   // bf16 1.0

  s16x8 bk[4][2];
  s16x8 bv[4][2];

  auto LOADK = [&](int j0s) {
    const ushort_t* kc = kb + (size_t)j0s * DHH;
#pragma unroll
    for (int nt = 0; nt < 4; nt++)
#pragma unroll
      for (int x = 0; x < 2; x++)
        bk[nt][x] = *(const s16x8*)&kc[(nt * 16 + l16) * DHH + x * 32 + quad * 8];
  };
  auto LOADV = [&](int j0s) {
    const ushort_t* vc = vtb + j0s;
#pragma unroll
    for (int dt = 0; dt < 4; dt++)
#pragma unroll
      for (int x = 0; x < 2; x++)
        bv[dt][x] = *(const s16x8*)&vc[(size_t)(dt * 16 + l16) * SS + x * 32 + quad * 8];
  };

  const int jlo = (q0 - (int)WW < (int)GG) ? (int)GG : (q0 - (int)WW);
  int jhi = q0 + (int)WW;
  if (jhi > SS - 64) jhi = SS - 64;

  int j0  = jlo;
  int j0u = __builtin_amdgcn_readfirstlane(j0);
  LOADK(j0u);

  bool last = false;
  while (!last) {
    int jn = j0 + 64;
    if (j0 == 0) { last = true; jn = 0; }
    else if (jn > jhi) jn = 0;               // wrap to the global chunk

    LOADV(j0u);

    const int dlt = j0 - q0;
    const bool needmask = (j0 != 0) && (dlt < -193 || dlt > 193);

#pragma unroll
    for (int nt = 0; nt < 4; nt++) {
      const int j = j0 + nt * 16 + l16;
#pragma unroll
      for (int mt = 0; mt < 4; mt++) {
        f32x4 s4 = {0.f, 0.f, 0.f, 0.f};
        s4 = __builtin_amdgcn_mfma_f32_16x16x32_bf16(aq[mt][0], bk[nt][0], s4, 0, 0, 0);
        s4 = __builtin_amdgcn_mfma_f32_16x16x32_bf16(aq[mt][1], bk[nt][1], s4, 0, 0, 0);
#pragma unroll
        for (int r = 0; r < 4; r++) {
          float p;
          if (needmask) {
            int i = q0 + mt * 16 + quad * 4 + r;
            int d = j - i;
            p = (d <= (int)WW && d >= -(int)WW) ? exp2f_fast(s4[r]) : 0.0f;
          } else {
            p = exp2f_fast(s4[r]);
          }
          Pw[wbase + nt * 1024 + mt * 128 + r * 8] = f2b1(p);
        }
      }
    }

    int jnu = __builtin_amdgcn_readfirstlane(jn);
    if (!last) LOADK(jnu);

    __builtin_amdgcn_s_setprio(1);
#pragma unroll
    for (int ll = 0; ll < 64; ll += 32) {
      s16x8 ap[4];
#pragma unroll
      for (int mt = 0; mt < 4; mt++)
        ap[mt] = *(const s16x8*)&Pw[rbase + (ll >> 3) * 512 + mt * 128];
#pragma unroll
      for (int mt = 0; mt < 4; mt++) {
        rsacc[mt] = __builtin_amdgcn_mfma_f32_16x16x32_bf16(ap[mt], vone, rsacc[mt], 0, 0, 0);
#pragma unroll
        for (int dt = 0; dt < 4; dt++)
          oacc[mt][dt] = __builtin_amdgcn_mfma_f32_16x16x32_bf16(ap[mt], bv[dt][ll >> 5], oacc[mt][dt], 0, 0, 0);
      }
    }
    __builtin_amdgcn_s_setprio(0);

    j0 = jn; j0u = jnu;
  }

#pragma unroll
  for (int mt = 0; mt < 4; mt++) {
#pragma unroll
    for (int r = 0; r < 4; r++) {
      float inv = __builtin_amdgcn_rcpf(rsacc[mt][r]);
      int srow2 = q0 + mt * 16 + quad * 4 + r;
      size_t orow = ((size_t)b * SS + srow2) * DD + h * DHH;
#pragma unroll
      for (int dt = 0; dt < 4; dt++)
        out[orow + dt * 16 + l16] = f2b1(oacc[mt][dt][r] * inv);
    }
  }
}

// ---------------------------------------------------------------------------
extern "C" void kernel_launch(void* const* d_in, const int* in_sizes, int n_in,
                              void* d_out, int out_size, void* d_ws, size_t ws_size,
                              hipStream_t stream) {
  const float *x, *Wq, *Wk, *Wv, *Wo;
  if (n_in == 5 && in_sizes[4] == 8388608) {   // alphabetical fallback
    Wk = (const float*)d_in[0]; Wo = (const float*)d_in[1];
    Wq = (const float*)d_in[2]; Wv = (const float*)d_in[3];
    x  = (const float*)d_in[4];
  } else {                                      // dict order (confirmed round 5/6)
    x  = (const float*)d_in[0]; Wq = (const float*)d_in[1];
    Wk = (const float*)d_in[2]; Wv = (const float*)d_in[3];
    Wo = (const float*)d_in[4];
  }
  float* out = (float*)d_out;   // fp32 output (confirmed round 6)

  // Workspace (72 MiB, proven available):
  // [WqT|WkT|WvT] 6MiB | WoT 2MiB | q 16MiB | k 16MiB | vT 16MiB | attn/xb 16MiB
  char* ws = (char*)d_ws;
  ushort_t* wqkvT = (ushort_t*)(ws);
  ushort_t* woT   = (ushort_t*)(ws + 6291456);
  ushort_t* qbuf  = (ushort_t*)(ws + 8388608);
  ushort_t* kbuf  = (ushort_t*)(ws + 8388608 + 16777216);
  ushort_t* vbuf  = (ushort_t*)(ws + 8388608 + 2 * 16777216);
  ushort_t* attn  = (ushort_t*)(ws + 8388608 + 3 * 16777216);
  ushort_t* xb    = attn;   // alias, lifetime-disjoint

  xcast<<<dim3(4096), 256, 0, stream>>>(x, xb);
  transpose_w<<<dim3(16, 16, 4), 256, 0, stream>>>(Wq, Wk, Wv, Wo, wqkvT);
  gemm256<<<dim3(32, 12), 512, 0, stream>>>(xb, wqkvT, qbuf, kbuf, vbuf, nullptr, 1024);
  attn_kernel<<<dim3(NBLK, HH, BB), 256, 0, stream>>>(qbuf, kbuf, vbuf, attn);
  gemmk128<<<dim3(64, 8), 256, 0, stream>>>(attn, woT, out, 1024);
}

// Round 9
// 234.274 us; speedup vs baseline: 1.1642x; 1.0206x over previous
//
#include <hip/hip_runtime.h>

// Problem constants
#define BB   2
#define SS   4096
#define DD   1024
#define HH   16
#define DHH  64
#define WW   256
#define GG   64
#define NBLK 16    // S/W

typedef unsigned short ushort_t;
typedef unsigned long long u64;
typedef short  s16x8 __attribute__((ext_vector_type(8)));
typedef float  f32x4 __attribute__((ext_vector_type(4)));

// 0.125 * log2(e): folded into q at QKV-GEMM epilogue time.
#define QSCALE 0.18033688011112042f

#define VMCNT(n) asm volatile("s_waitcnt vmcnt(" #n ")" ::: "memory")

// fp32 -> bf16 round-to-nearest-even, raw bits
__device__ __forceinline__ ushort_t f2b(float f) {
  unsigned int u = __builtin_bit_cast(unsigned int, f);
  unsigned int r = (u + 0x7fffu + ((u >> 16) & 1u)) >> 16;
  return (ushort_t)r;
}

// single-op fp32 -> bf16 (RNE) via v_cvt_pk_bf16_f32, low half used
__device__ __forceinline__ ushort_t f2b1(float f) {
  unsigned int r;
  asm("v_cvt_pk_bf16_f32 %0, %1, %2" : "=v"(r) : "v"(f), "v"(f));
  return (ushort_t)r;
}

// pack two fp32 -> one u32 of 2 bf16 (low = a, high = b)
__device__ __forceinline__ unsigned int pk2(float a, float b) {
  unsigned int r;
  asm("v_cvt_pk_bf16_f32 %0, %1, %2" : "=v"(r) : "v"(a), "v"(b));
  return r;
}

__device__ __forceinline__ float exp2f_fast(float x) {
  return __builtin_amdgcn_exp2f(x);
}

// Async 16B global->LDS DMA. LDS dst must be wave-uniform base + lane*16.
__device__ __forceinline__ void gld16(const void* g, void* l) {
  __builtin_amdgcn_global_load_lds(
      (const __attribute__((address_space(1))) void*)g,
      (__attribute__((address_space(3))) void*)l, 16, 0, 0);
}

// ---------------------------------------------------------------------------
// x (fp32) -> bf16, flat. 4096 blocks x 256 thr x 8 elems.
// ---------------------------------------------------------------------------
__global__ __launch_bounds__(256) void xcast(
    const float* __restrict__ x, ushort_t* __restrict__ xb) {
  size_t i = ((size_t)blockIdx.x * 256 + threadIdx.x) * 8;
  float4 f0 = *(const float4*)&x[i];
  float4 f1 = *(const float4*)&x[i + 4];
  ushort_t t[8];
  t[0] = f2b(f0.x); t[1] = f2b(f0.y); t[2] = f2b(f0.z); t[3] = f2b(f0.w);
  t[4] = f2b(f1.x); t[5] = f2b(f1.y); t[6] = f2b(f1.z); t[7] = f2b(f1.w);
  *(uint4*)&xb[i] = *(const uint4*)t;
}

// ---------------------------------------------------------------------------
// Transpose + fp32->bf16 the four weight matrices into (n,k) bf16 layout.
// ---------------------------------------------------------------------------
__global__ __launch_bounds__(256) void transpose_w(
    const float* __restrict__ Wq, const float* __restrict__ Wk,
    const float* __restrict__ Wv, const float* __restrict__ Wo,
    ushort_t* __restrict__ outBase) {
  const float* src = (blockIdx.z == 0) ? Wq : (blockIdx.z == 1) ? Wk
                    : (blockIdx.z == 2) ? Wv : Wo;
  ushort_t* dst = outBase + (size_t)blockIdx.z * (1024 * 1024);
  __shared__ __align__(16) ushort_t t[64][72];
  const int tid = threadIdx.x;
  const int bx = blockIdx.x * 64, by = blockIdx.y * 64;
  const int c4 = (tid & 15) * 4;
  const int r16 = tid >> 4;
  for (int rr = r16; rr < 64; rr += 16) {
    float4 f = *(const float4*)&src[(size_t)(by + rr) * 1024 + bx + c4];
    t[c4 + 0][rr] = f2b(f.x);
    t[c4 + 1][rr] = f2b(f.y);
    t[c4 + 2][rr] = f2b(f.z);
    t[c4 + 3][rr] = f2b(f.w);
  }
  __syncthreads();
  const int sr = tid >> 3;
  const int sc = (tid & 7) * 8;
  for (int rr = sr; rr < 64; rr += 32) {
    *(uint4*)&dst[(size_t)(bx + rr) * 1024 + by + sc] = *(const uint4*)&t[rr][sc];
  }
}

// ---------------------------------------------------------------------------
// QKV GEMM: 256x256 tile, 8-phase pipelined schedule — EXACT round-4/6 kernel
// (best measured: ~75 us). 2-D super-tile XCD swizzle + v-block LDS-transpose
// epilogue. See round-4 comments for the vmcnt/slab ledger.
// ---------------------------------------------------------------------------
__global__ __launch_bounds__(512, 2) void gemm256(
    const ushort_t* __restrict__ A, const ushort_t* __restrict__ Bt,
    ushort_t* __restrict__ O0, ushort_t* __restrict__ O1,
    ushort_t* __restrict__ O2, float* __restrict__ Of, int K) {
  __shared__ __align__(16) ushort_t SH[65536];

  const int tid  = threadIdx.x;        // 0..511
  const int lane = tid & 63;
  const int w    = tid >> 6;           // 0..7
  const int quad = lane >> 4;          // 0..3
  const int l16  = lane & 15;
  const int wr   = w >> 2;             // 0..1  (M)
  const int wc   = w & 3;              // 0..3  (N)

  // 2-D super-tile XCD swizzle (gridDim.x must be 32)
  const int id  = blockIdx.x + (gridDim.x * blockIdx.y);
  const int xcd = id & 7;
  const int seq = id >> 3;
  const int nx  = (xcd << 2) + (seq & 3);
  const int ny  = seq >> 2;
  const int bm  = nx * 256;
  const int bn  = ny * 256;

  auto Aslab = [&](int buf, int kkh) -> ushort_t* {
    return &SH[(buf * 2 + kkh) * 8192];
  };
  auto Bslab = [&](int buf, int kkh) -> ushort_t* {
    return &SH[32768 + (buf * 2 + kkh) * 8192];
  };

  const int srow = tid >> 2;                        // 0..127
  const int sch  = (tid & 3) ^ ((srow >> 1) & 3);   // source 16B chunk in row
  const ushort_t* Ag = A + (size_t)(bm + srow) * K + sch * 8;
  const ushort_t* Bg = Bt + (size_t)(bn + srow) * K + sch * 8;

  const int chofs = ((quad ^ ((l16 >> 1) & 3)) << 3);

  auto stage = [&](ushort_t* slab, const ushort_t* g) {
    gld16(g, &slab[tid * 8]);
    gld16(g + (size_t)128 * K, &slab[4096 + tid * 8]);
  };

  f32x4 acc[8][4] = {};
  s16x8 afrag[4], bfrag[4];

  auto ldA = [&](int buf, int kkh, int i) {
    const int row = wr * 128 + i * 16 + l16;
    return *(const s16x8*)&Aslab(buf, kkh)[row * 32 + chofs];
  };
  auto ldB = [&](int buf, int kkh, int j) {
    const int row = wc * 64 + j * 16 + l16;
    return *(const s16x8*)&Bslab(buf, kkh)[row * 32 + chofs];
  };
  auto mfma16 = [&](int ih) {
    __builtin_amdgcn_s_setprio(1);
#pragma unroll
    for (int t = 0; t < 4; t++)
#pragma unroll
      for (int j = 0; j < 4; j++)
        acc[ih * 4 + t][j] = __builtin_amdgcn_mfma_f32_16x16x32_bf16(
            afrag[t], bfrag[j], acc[ih * 4 + t][j], 0, 0, 0);
    __builtin_amdgcn_s_setprio(0);
  };

  const int NT = K >> 6;

  stage(Bslab(0, 0), Bg);
  stage(Aslab(0, 0), Ag);
  stage(Bslab(0, 1), Bg + 32);
  stage(Aslab(0, 1), Ag + 32);
  VMCNT(4);
  stage(Bslab(1, 0), Bg + 64);
  stage(Aslab(1, 0), Ag + 64);
  stage(Bslab(1, 1), Bg + 96);
  VMCNT(6);
  __builtin_amdgcn_s_barrier();

#pragma unroll 1
  for (int kt = 0; kt < NT; ++kt) {
    const int buf = kt & 1;
    // phase 1: kk0, m 0..3
#pragma unroll
    for (int j = 0; j < 4; j++) bfrag[j] = ldB(buf, 0, j);
#pragma unroll
    for (int t = 0; t < 4; t++) afrag[t] = ldA(buf, 0, t);
    if (kt + 1 < NT) stage(Aslab(buf ^ 1, 1), Ag + (size_t)(kt + 1) * 64 + 32);
    __builtin_amdgcn_s_barrier();
    asm volatile("s_waitcnt lgkmcnt(0)" ::: "memory");
    mfma16(0);
    __builtin_amdgcn_s_barrier();
    // phase 2: kk0, m 4..7
#pragma unroll
    for (int t = 0; t < 4; t++) afrag[t] = ldA(buf, 0, 4 + t);
    if (kt + 2 < NT) stage(Bslab(buf, 0), Bg + (size_t)(kt + 2) * 64);
    __builtin_amdgcn_s_barrier();
    asm volatile("s_waitcnt lgkmcnt(0)" ::: "memory");
    mfma16(1);
    __builtin_amdgcn_s_barrier();
    // phase 3: kk1, m 0..3
#pragma unroll
    for (int j = 0; j < 4; j++) bfrag[j] = ldB(buf, 1, j);
#pragma unroll
    for (int t = 0; t < 4; t++) afrag[t] = ldA(buf, 1, t);
    if (kt + 2 < NT) stage(Aslab(buf, 0), Ag + (size_t)(kt + 2) * 64);
    __builtin_amdgcn_s_barrier();
    asm volatile("s_waitcnt lgkmcnt(0)" ::: "memory");
    mfma16(0);
    __builtin_amdgcn_s_barrier();
    // phase 4: kk1, m 4..7; counted vmcnt
#pragma unroll
    for (int t = 0; t < 4; t++) afrag[t] = ldA(buf, 1, 4 + t);
    if (kt + 2 < NT) {
      stage(Bslab(buf, 1), Bg + (size_t)(kt + 2) * 64 + 32);
      VMCNT(6);
    } else if (kt + 1 < NT) {
      VMCNT(0);
    }
    __builtin_amdgcn_s_barrier();
    asm volatile("s_waitcnt lgkmcnt(0)" ::: "memory");
    mfma16(1);
    __builtin_amdgcn_s_barrier();
  }

  // Epilogue. C/D layout: row = quad*4 + reg, col = lane&15.
  if (bn >= 2048) {
    // v-block: LDS transpose, coalesced 16B stores.
    const int bb = bm >> 12;
    const int n1b = bn & 1023;
    const int sb  = bm & 4095;
#pragma unroll 1
    for (int p = 0; p < 2; p++) {
      __syncthreads();
      if (wr == p) {
#pragma unroll
        for (int i = 0; i < 8; i++)
#pragma unroll
          for (int j = 0; j < 4; j++)
#pragma unroll
            for (int r = 0; r < 4; r++)
              SH[(wc * 64 + j * 16 + l16) * 136 + i * 16 + quad * 4 + r] =
                  f2b(acc[i][j][r]);
      }
      __syncthreads();
#pragma unroll
      for (int it = 0; it < 8; it++) {
        const int row = it * 32 + (tid >> 4);
        const int n1 = n1b + row;
        const int dh = n1 & 63, hh = n1 >> 6;
        const int s = sb + p * 128 + (tid & 15) * 8;
        uint4 val = *(const uint4*)&SH[row * 136 + (tid & 15) * 8];
        *(uint4*)&O2[(((size_t)bb * HH + hh) * DHH + dh) * SS + s] = val;
      }
    }
  } else {
#pragma unroll
    for (int i = 0; i < 8; i++) {
#pragma unroll
      for (int j = 0; j < 4; j++) {
#pragma unroll
        for (int r = 0; r < 4; r++) {
          int m = bm + wr * 128 + i * 16 + quad * 4 + r;
          int n = bn + wc * 64 + j * 16 + l16;
          float av = acc[i][j][r];
          int n1 = n & 1023;
          int h = n1 >> 6, dh = n1 & 63;
          int b = m >> 12, s = m & 4095;
          if (n < 1024) {
            O0[(((size_t)b * HH + h) * SS + s) * DHH + dh] = f2b(av * QSCALE);
          } else {
            O1[(((size_t)b * HH + h) * SS + s) * DHH + dh] = f2b(av);
          }
        }
      }
    }
  }
}

// ---------------------------------------------------------------------------
// Output-projection GEMM (unchanged from round 6): 128x128 tile, BK=32,
// double-buffered 32 KiB LDS, 4 blocks/CU, counted VMCNT(4), XCD swizzle.
// ---------------------------------------------------------------------------
__global__ __launch_bounds__(256, 4) void gemmk128(
    const ushort_t* __restrict__ A, const ushort_t* __restrict__ Bt,
    float* __restrict__ Of, int K) {
  __shared__ __align__(16) ushort_t As[2][128 * 32];
  __shared__ __align__(16) ushort_t Bs[2][128 * 32];

  const int tid  = threadIdx.x;        // 0..255
  const int lane = tid & 63;
  const int w    = tid >> 6;           // 0..3
  const int quad = lane >> 4;
  const int l16  = lane & 15;
  const int wr   = w >> 1;             // 0..1 (M)
  const int wc   = w & 1;              // 0..1 (N)

  // 2-D super-tile XCD swizzle (gridDim.x == 64)
  const int id  = blockIdx.x + (gridDim.x * blockIdx.y);
  const int xcd = id & 7;
  const int seq = id >> 3;
  const int nx  = (xcd << 3) + (seq & 7);
  const int ny  = seq >> 3;
  const int bm  = nx * 128;
  const int bn  = ny * 128;

  const int srow = tid >> 2;                        // 0..63
  const int sch  = (tid & 3) ^ ((srow >> 1) & 3);
  const ushort_t* Ag = A + (size_t)(bm + srow) * K + sch * 8;
  const ushort_t* Bg = Bt + (size_t)(bn + srow) * K + sch * 8;
  const int sch2 = (tid & 3) ^ (((srow + 64) >> 1) & 3);
  const ushort_t* Ag2 = A + (size_t)(bm + srow + 64) * K + sch2 * 8;
  const ushort_t* Bg2 = Bt + (size_t)(bn + srow + 64) * K + sch2 * 8;

  const int chofs = ((quad ^ ((l16 >> 1) & 3)) << 3);

  auto stage = [&](int buf, int s) {
    gld16(Ag + (size_t)s * 32, &As[buf][tid * 8]);
    gld16(Ag2 + (size_t)s * 32, &As[buf][2048 + tid * 8]);
    gld16(Bg + (size_t)s * 32, &Bs[buf][tid * 8]);
    gld16(Bg2 + (size_t)s * 32, &Bs[buf][2048 + tid * 8]);
  };

  f32x4 acc[4][4] = {};

  const int NT = K >> 5;   // 32 K-steps

  stage(0, 0);
  VMCNT(0);
  __builtin_amdgcn_s_barrier();

#pragma unroll 1
  for (int s = 0; s < NT; ++s) {
    const int buf = s & 1;
    if (s + 1 < NT) {
      stage(buf ^ 1, s + 1);
      VMCNT(4);                      // stage(s) landed; stage(s+1) in flight
    } else {
      VMCNT(0);
    }
    __builtin_amdgcn_s_barrier();
    s16x8 afrag[4], bfrag[4];
#pragma unroll
    for (int t = 0; t < 4; t++)
      afrag[t] = *(const s16x8*)&As[buf][(wr * 64 + t * 16 + l16) * 32 + chofs];
#pragma unroll
    for (int j = 0; j < 4; j++)
      bfrag[j] = *(const s16x8*)&Bs[buf][(wc * 64 + j * 16 + l16) * 32 + chofs];
    asm volatile("s_waitcnt lgkmcnt(0)" ::: "memory");
    __builtin_amdgcn_s_setprio(1);
#pragma unroll
    for (int t = 0; t < 4; t++)
#pragma unroll
      for (int j = 0; j < 4; j++)
        acc[t][j] = __builtin_amdgcn_mfma_f32_16x16x32_bf16(
            afrag[t], bfrag[j], acc[t][j], 0, 0, 0);
    __builtin_amdgcn_s_setprio(0);
    __builtin_amdgcn_s_barrier();
  }

  // Epilogue: fp32 row-major. C/D: row = quad*4 + r, col = l16.
#pragma unroll
  for (int i = 0; i < 4; i++) {
#pragma unroll
    for (int j = 0; j < 4; j++) {
#pragma unroll
      for (int r = 0; r < 4; r++) {
        int m = bm + wr * 64 + i * 16 + quad * 4 + r;
        int n = bn + wc * 64 + j * 16 + l16;
        Of[(size_t)m * DD + n] = acc[i][j][r];
      }
    }
  }
}

// ---------------------------------------------------------------------------
// Attention v5: v3 structure (barrier-free, wave-independent, prefetched K/V)
// with a SWAPPED-OPERAND QK^T so the P LDS round-trip is conflict-free using
// only plain ds ops (tr_read abandoned after round-8 correctness failure):
//   QK computes S^T = mfma(K_frag, Q_frag): lane (quad,l16) reg r holds
//   S[k = nt*16 + quad*4 + r][q = mt*16 + l16] — 4 CONSECUTIVE k per lane.
//   P tile: row-major [q][k] with chunk-XOR swizzle:
//     elem(q,k) = q*64 + (((k>>3) ^ (q&7))<<3) + (k&7)
//   Write: 16 x b64 (2 cvt_pk packs) per chunk, banks uniform.
//   Read (PV A-frag, q-row, 8 consecutive k): b128 at the same swizzle,
//     banks uniform. Verified both sides index-by-index vs the layout.
//   Mask: d = (j0 + nt*16 + quad*4 + r) - (q0 + mt*16 + l16).
//   rsacc/oacc/epilogue layouts unchanged (A-frag rows are still q).
// ---------------------------------------------------------------------------
__global__ __launch_bounds__(256, 2) void attn_kernel(
    const ushort_t* __restrict__ q, const ushort_t* __restrict__ k,
    const ushort_t* __restrict__ vT, ushort_t* __restrict__ out) {
  const int blk = blockIdx.x;
  const int h   = blockIdx.y;
  const int b   = blockIdx.z;
  const int tid  = threadIdx.x;
  const int lane = tid & 63;
  const int w    = tid >> 6;
  const int quad = lane >> 4;
  const int l16  = lane & 15;
  const int l7   = l16 & 7;

  const size_t bh = ((size_t)b * HH + h) * SS * DHH;
  const ushort_t* qb  = q + bh;
  const ushort_t* kb  = k + bh;
  const ushort_t* vtb = vT + bh;   // layout [dh][s], row stride SS

  __shared__ __align__(16) ushort_t Ps[4][64 * 64];   // per-wave P tiles (8KB)
  ushort_t* Pw = &Ps[w][0];

  const int q0 = blk * WW + w * 64;

  // P elem offsets (layout above). Write per (mt,nt): 4 k-values contiguous.
  const int wofs = l16 * 64 + 4 * (quad & 1);     // + mt*1024 + chunk'(nt)*8
  const int hq1  = quad >> 1;
  const int rofs = l16 * 64;                      // + mt*1024 + chunkR*8

  s16x8 aq[4][2];
#pragma unroll
  for (int mt = 0; mt < 4; mt++)
#pragma unroll
    for (int x = 0; x < 2; x++)
      aq[mt][x] = *(const s16x8*)&qb[(size_t)(q0 + mt * 16 + l16) * DHH + x * 32 + quad * 8];

  f32x4 oacc[4][4] = {};
  f32x4 rsacc[4] = {};

  s16x8 vone;
#pragma unroll
  for (int j = 0; j < 8; j++) vone[j] = (short)0x3F80;   // bf16 1.0

  s16x8 bk[4][2];
  s16x8 bv[4][2];

  auto LOADK = [&](int j0s) {
    const ushort_t* kc = kb + (size_t)j0s * DHH;
#pragma unroll
    for (int nt = 0; nt < 4; nt++)
#pragma unroll
      for (int x = 0; x < 2; x++)
        bk[nt][x] = *(const s16x8*)&kc[(nt * 16 + l16) * DHH + x * 32 + quad * 8];
  };
  auto LOADV = [&](int j0s) {
    const ushort_t* vc = vtb + j0s;
#pragma unroll
    for (int dt = 0; dt < 4; dt++)
#pragma unroll
      for (int x = 0; x < 2; x++)
        bv[dt][x] = *(const s16x8*)&vc[(size_t)(dt * 16 + l16) * SS + x * 32 + quad * 8];
  };

  const int jlo = (q0 - (int)WW < (int)GG) ? (int)GG : (q0 - (int)WW);
  int jhi = q0 + (int)WW;
  if (jhi > SS - 64) jhi = SS - 64;

  int j0  = jlo;
  int j0u = __builtin_amdgcn_readfirstlane(j0);
  LOADK(j0u);

  bool last = false;
  while (!last) {
    int jn = j0 + 64;
    if (j0 == 0) { last = true; jn = 0; }
    else if (jn > jhi) jn = 0;               // wrap to the global chunk

    LOADV(j0u);

    const int dlt = j0 - q0;
    const bool needmask = (j0 != 0) && (dlt < -193 || dlt > 193);

    // --- QK^T (swapped: S^T) + exp2 + packed b64 P-writes ---
#pragma unroll
    for (int nt = 0; nt < 4; nt++) {
      const int jbase = j0 + nt * 16 + quad * 4;     // k index of reg r=0
#pragma unroll
      for (int mt = 0; mt < 4; mt++) {
        f32x4 s4 = {0.f, 0.f, 0.f, 0.f};
        s4 = __builtin_amdgcn_mfma_f32_16x16x32_bf16(bk[nt][0], aq[mt][0], s4, 0, 0, 0);
        s4 = __builtin_amdgcn_mfma_f32_16x16x32_bf16(bk[nt][1], aq[mt][1], s4, 0, 0, 0);
        float p[4];
#pragma unroll
        for (int r = 0; r < 4; r++) {
          if (needmask) {
            int d = jbase + r - (q0 + mt * 16 + l16);
            p[r] = (d <= (int)WW && d >= -(int)WW) ? exp2f_fast(s4[r]) : 0.0f;
          } else {
            p[r] = exp2f_fast(s4[r]);
          }
        }
        unsigned int lo = pk2(p[0], p[1]);
        unsigned int hi = pk2(p[2], p[3]);
        u64 val = __builtin_bit_cast(u64, (uint2){lo, hi});
        const int ch = ((nt << 1) | hq1) ^ l7;       // swizzled 8-elem chunk
        *(u64*)&Pw[wofs + mt * 1024 + ch * 8] = val;
      }
    }

    int jnu = __builtin_amdgcn_readfirstlane(jn);
    if (!last) LOADK(jnu);

    // --- PV + ones-MFMA row sums (A-frags via swizzled b128 reads) ---
    __builtin_amdgcn_s_setprio(1);
#pragma unroll
    for (int ll = 0; ll < 64; ll += 32) {
      s16x8 ap[4];
#pragma unroll
      for (int mt = 0; mt < 4; mt++) {
        const int chR = (quad + (ll >> 3)) ^ l7;
        ap[mt] = *(const s16x8*)&Pw[rofs + mt * 1024 + chR * 8];
      }
#pragma unroll
      for (int mt = 0; mt < 4; mt++) {
        rsacc[mt] = __builtin_amdgcn_mfma_f32_16x16x32_bf16(ap[mt], vone, rsacc[mt], 0, 0, 0);
#pragma unroll
        for (int dt = 0; dt < 4; dt++)
          oacc[mt][dt] = __builtin_amdgcn_mfma_f32_16x16x32_bf16(ap[mt], bv[dt][ll >> 5], oacc[mt][dt], 0, 0, 0);
      }
    }
    __builtin_amdgcn_s_setprio(0);

    j0 = jn; j0u = jnu;
  }

#pragma unroll
  for (int mt = 0; mt < 4; mt++) {
#pragma unroll
    for (int r = 0; r < 4; r++) {
      float inv = __builtin_amdgcn_rcpf(rsacc[mt][r]);
      int srow2 = q0 + mt * 16 + quad * 4 + r;
      size_t orow = ((size_t)b * SS + srow2) * DD + h * DHH;
#pragma unroll
      for (int dt = 0; dt < 4; dt++)
        out[orow + dt * 16 + l16] = f2b1(oacc[mt][dt][r] * inv);
    }
  }
}

// ---------------------------------------------------------------------------
extern "C" void kernel_launch(void* const* d_in, const int* in_sizes, int n_in,
                              void* d_out, int out_size, void* d_ws, size_t ws_size,
                              hipStream_t stream) {
  const float *x, *Wq, *Wk, *Wv, *Wo;
  if (n_in == 5 && in_sizes[4] == 8388608) {   // alphabetical fallback
    Wk = (const float*)d_in[0]; Wo = (const float*)d_in[1];
    Wq = (const float*)d_in[2]; Wv = (const float*)d_in[3];
    x  = (const float*)d_in[4];
  } else {                                      // dict order (confirmed round 5/6)
    x  = (const float*)d_in[0]; Wq = (const float*)d_in[1];
    Wk = (const float*)d_in[2]; Wv = (const float*)d_in[3];
    Wo = (const float*)d_in[4];
  }
  float* out = (float*)d_out;   // fp32 output (confirmed round 6)

  // Workspace (72 MiB, proven available):
  // [WqT|WkT|WvT] 6MiB | WoT 2MiB | q 16MiB | k 16MiB | vT 16MiB | attn/xb 16MiB
  char* ws = (char*)d_ws;
  ushort_t* wqkvT = (ushort_t*)(ws);
  ushort_t* woT   = (ushort_t*)(ws + 6291456);
  ushort_t* qbuf  = (ushort_t*)(ws + 8388608);
  ushort_t* kbuf  = (ushort_t*)(ws + 8388608 + 16777216);
  ushort_t* vbuf  = (ushort_t*)(ws + 8388608 + 2 * 16777216);
  ushort_t* attn  = (ushort_t*)(ws + 8388608 + 3 * 16777216);
  ushort_t* xb    = attn;   // alias, lifetime-disjoint

  xcast<<<dim3(4096), 256, 0, stream>>>(x, xb);
  transpose_w<<<dim3(16, 16, 4), 256, 0, stream>>>(Wq, Wk, Wv, Wo, wqkvT);
  gemm256<<<dim3(32, 12), 512, 0, stream>>>(xb, wqkvT, qbuf, kbuf, vbuf, nullptr, 1024);
  attn_kernel<<<dim3(NBLK, HH, BB), 256, 0, stream>>>(qbuf, kbuf, vbuf, attn);
  gemmk128<<<dim3(64, 8), 256, 0, stream>>>(attn, woT, out, 1024);
}